// Round 1
// baseline (1179.359 us; speedup 1.0000x reference)
//
#include <hip/hip_runtime.h>

#define H 128

// ---------------------------------------------------------------------------
// GEMM: s[n][j] = sum_k x[n][k] * W[j][k] + b[j]   (W is [H][H], row-major)
// Block: 256 threads. Stage W transposed into LDS (k-major, 64KB), stage 32
// x-rows (16KB). Thread tile: 4 rows x 4 cols.  2 blocks/CU (80KB LDS).
// ---------------------------------------------------------------------------
#define GEMM_ROWS 32
#define GEMM_BLK 256

__global__ __launch_bounds__(GEMM_BLK) void gemm_kernel(
    const float* __restrict__ x, const float* __restrict__ W,
    const float* __restrict__ b, float* __restrict__ s, int N)
{
    __shared__ float Wt[H * H];          // Wt[k*H + j] = W[j*H + k]  (64 KB)
    __shared__ float xs[GEMM_ROWS * H];  // 16 KB

    const int t = threadIdx.x;

    // stage W transposed (one-time per block; write conflicts acceptable)
    for (int idx = t; idx < H * H; idx += GEMM_BLK) {
        int j = idx >> 7;
        int k = idx & (H - 1);
        Wt[k * H + j] = W[idx];
    }

    const int tc = t & 31;   // col group: cols 4*tc .. 4*tc+3
    const int tg = t >> 5;   // row group 0..7: rows tg*4 .. tg*4+3
    const float4 bias = *reinterpret_cast<const float4*>(b + 4 * tc);

    const int nbatch = (N + GEMM_ROWS - 1) / GEMM_ROWS;
    for (int batch = blockIdx.x; batch < nbatch; batch += gridDim.x) {
        const int row0 = batch * GEMM_ROWS;

        __syncthreads();  // protect xs (and Wt on first iter)
        // stage 32 x-rows as float4s (1024 float4s, 4 per thread)
        for (int idx = t; idx < GEMM_ROWS * H / 4; idx += GEMM_BLK) {
            int r = idx >> 5;       // 32 float4 per row
            int c4 = idx & 31;
            int gr = row0 + r;
            float4 v = make_float4(0.f, 0.f, 0.f, 0.f);
            if (gr < N) v = *reinterpret_cast<const float4*>(x + (size_t)gr * H + c4 * 4);
            *reinterpret_cast<float4*>(xs + r * H + c4 * 4) = v;
        }
        __syncthreads();

        float4 acc0 = make_float4(0.f, 0.f, 0.f, 0.f);
        float4 acc1 = acc0, acc2 = acc0, acc3 = acc0;
        const float* xr0 = xs + (tg * 4 + 0) * H;
        const float* xr1 = xs + (tg * 4 + 1) * H;
        const float* xr2 = xs + (tg * 4 + 2) * H;
        const float* xr3 = xs + (tg * 4 + 3) * H;

        #pragma unroll 4
        for (int k = 0; k < H; ++k) {
            float4 w4 = *reinterpret_cast<const float4*>(Wt + k * H + 4 * tc);
            float x0 = xr0[k], x1 = xr1[k], x2 = xr2[k], x3 = xr3[k];
            acc0.x += w4.x * x0; acc0.y += w4.y * x0; acc0.z += w4.z * x0; acc0.w += w4.w * x0;
            acc1.x += w4.x * x1; acc1.y += w4.y * x1; acc1.z += w4.z * x1; acc1.w += w4.w * x1;
            acc2.x += w4.x * x2; acc2.y += w4.y * x2; acc2.z += w4.z * x2; acc2.w += w4.w * x2;
            acc3.x += w4.x * x3; acc3.y += w4.y * x3; acc3.z += w4.z * x3; acc3.w += w4.w * x3;
        }

        float4 accs[4] = {acc0, acc1, acc2, acc3};
        #pragma unroll
        for (int rr = 0; rr < 4; ++rr) {
            int row = row0 + tg * 4 + rr;
            if (row < N) {
                float4 o = accs[rr];
                o.x += bias.x; o.y += bias.y; o.z += bias.z; o.w += bias.w;
                *reinterpret_cast<float4*>(s + (size_t)row * H + 4 * tc) = o;
            }
        }
    }
}

// ---------------------------------------------------------------------------
// init: out[n][j] = gbias[j]
// ---------------------------------------------------------------------------
__global__ __launch_bounds__(256) void init_out_kernel(
    float* __restrict__ out, const float* __restrict__ gbias, int total4)
{
    int i = blockIdx.x * blockDim.x + threadIdx.x;
    const int stride = gridDim.x * blockDim.x;
    for (; i < total4; i += stride) {
        int c4 = i & 31;  // H/4 = 32 float4 per row
        float4 bv = *reinterpret_cast<const float4*>(gbias + c4 * 4);
        *reinterpret_cast<float4*>(out + (size_t)i * 4) = bv;
    }
}

// ---------------------------------------------------------------------------
// SpMM edges: out[row[e]] += w[e] * s[col[e]]   (one wave per edge, 2 f/lane)
// ---------------------------------------------------------------------------
__global__ __launch_bounds__(256) void spmm_edge_kernel(
    const int* __restrict__ erow, const int* __restrict__ ecol,
    const float* __restrict__ ew, const float* __restrict__ s,
    float* __restrict__ out, int E)
{
    long long gid = (long long)blockIdx.x * blockDim.x + threadIdx.x;
    int e = (int)(gid >> 6);
    int l = (int)(gid & 63);
    if (e >= E) return;
    int r = erow[e];
    int c = ecol[e];
    float w = ew[e];
    float2 v = *reinterpret_cast<const float2*>(s + (size_t)c * H + l * 2);
    unsafeAtomicAdd(out + (size_t)r * H + l * 2 + 0, v.x * w);
    unsafeAtomicAdd(out + (size_t)r * H + l * 2 + 1, v.y * w);
}

// ---------------------------------------------------------------------------
// PReLU (in place): v = v > 0 ? v : a*v
// ---------------------------------------------------------------------------
__global__ __launch_bounds__(256) void prelu_kernel(
    float* __restrict__ buf, const float* __restrict__ a_ptr, int total4)
{
    const float a = a_ptr[0];
    int i = blockIdx.x * blockDim.x + threadIdx.x;
    const int stride = gridDim.x * blockDim.x;
    for (; i < total4; i += stride) {
        float4 v = *reinterpret_cast<float4*>(buf + (size_t)i * 4);
        v.x = v.x > 0.f ? v.x : a * v.x;
        v.y = v.y > 0.f ? v.y : a * v.y;
        v.z = v.z > 0.f ? v.z : a * v.z;
        v.w = v.w > 0.f ? v.w : a * v.w;
        *reinterpret_cast<float4*>(buf + (size_t)i * 4) = v;
    }
}

// ---------------------------------------------------------------------------
extern "C" void kernel_launch(void* const* d_in, const int* in_sizes, int n_in,
                              void* d_out, int out_size, void* d_ws, size_t ws_size,
                              hipStream_t stream)
{
    const float* h        = (const float*)d_in[0];
    const int*   erow     = (const int*)d_in[1];
    const int*   ecol     = (const int*)d_in[2];
    const float* ew       = (const float*)d_in[3];
    const float* fc_w     = (const float*)d_in[4];  // [2][H][H]
    const float* fc_b     = (const float*)d_in[5];  // [2][H]
    const float* gcn_bias = (const float*)d_in[6];  // [2][H]
    const float* prelu_a  = (const float*)d_in[7];  // [2]

    const int N = in_sizes[0] / H;
    const int E = in_sizes[1];
    float* out = (float*)d_out;
    float* s   = (float*)d_ws;      // N*H floats scratch (51.2 MB)

    const int total4 = N * (H / 4);
    const int spmm_blocks = (int)(((long long)E * 64 + 255) / 256);

    // ---- layer 0 ----  x = h
    gemm_kernel<<<512, GEMM_BLK, 0, stream>>>(h, fc_w, fc_b, s, N);
    init_out_kernel<<<2048, 256, 0, stream>>>(out, gcn_bias, total4);
    spmm_edge_kernel<<<spmm_blocks, 256, 0, stream>>>(erow, ecol, ew, s, out, E);
    prelu_kernel<<<2048, 256, 0, stream>>>(out, prelu_a, total4);
    // d_out now holds x1

    // ---- layer 1 ----  x = d_out
    gemm_kernel<<<512, GEMM_BLK, 0, stream>>>(out, fc_w + H * H, fc_b + H, s, N);
    init_out_kernel<<<2048, 256, 0, stream>>>(out, gcn_bias + H, total4);
    spmm_edge_kernel<<<spmm_blocks, 256, 0, stream>>>(erow, ecol, ew, s, out, E);
    prelu_kernel<<<2048, 256, 0, stream>>>(out, prelu_a + 1, total4);
}

// Round 2
// 326.905 us; speedup vs baseline: 3.6076x; 3.6076x over previous
//
#include <hip/hip_runtime.h>

#define H 128

// ===========================================================================
// GEMM: s[n][j] = sum_k x[n][k] * W[j][k] + b[j]   (W is [H][H], row-major)
// ===========================================================================
#define GEMM_ROWS 32
#define GEMM_BLK 256

__global__ __launch_bounds__(GEMM_BLK) void gemm_kernel(
    const float* __restrict__ x, const float* __restrict__ W,
    const float* __restrict__ b, float* __restrict__ s, int N)
{
    __shared__ float Wt[H * H];          // Wt[k*H + j] = W[j*H + k]  (64 KB)
    __shared__ float xs[GEMM_ROWS * H];  // 16 KB

    const int t = threadIdx.x;

    for (int idx = t; idx < H * H; idx += GEMM_BLK) {
        int j = idx >> 7;
        int k = idx & (H - 1);
        Wt[k * H + j] = W[idx];
    }

    const int tc = t & 31;   // cols 4*tc .. 4*tc+3
    const int tg = t >> 5;   // rows tg*4 .. tg*4+3
    const float4 bias = *reinterpret_cast<const float4*>(b + 4 * tc);

    const int nbatch = (N + GEMM_ROWS - 1) / GEMM_ROWS;
    for (int batch = blockIdx.x; batch < nbatch; batch += gridDim.x) {
        const int row0 = batch * GEMM_ROWS;

        __syncthreads();
        for (int idx = t; idx < GEMM_ROWS * H / 4; idx += GEMM_BLK) {
            int r = idx >> 5;
            int c4 = idx & 31;
            int gr = row0 + r;
            float4 v = make_float4(0.f, 0.f, 0.f, 0.f);
            if (gr < N) v = *reinterpret_cast<const float4*>(x + (size_t)gr * H + c4 * 4);
            *reinterpret_cast<float4*>(xs + r * H + c4 * 4) = v;
        }
        __syncthreads();

        float4 acc0 = make_float4(0.f, 0.f, 0.f, 0.f);
        float4 acc1 = acc0, acc2 = acc0, acc3 = acc0;
        const float* xr0 = xs + (tg * 4 + 0) * H;
        const float* xr1 = xs + (tg * 4 + 1) * H;
        const float* xr2 = xs + (tg * 4 + 2) * H;
        const float* xr3 = xs + (tg * 4 + 3) * H;

        #pragma unroll 4
        for (int k = 0; k < H; ++k) {
            float4 w4 = *reinterpret_cast<const float4*>(Wt + k * H + 4 * tc);
            float x0 = xr0[k], x1 = xr1[k], x2 = xr2[k], x3 = xr3[k];
            acc0.x += w4.x * x0; acc0.y += w4.y * x0; acc0.z += w4.z * x0; acc0.w += w4.w * x0;
            acc1.x += w4.x * x1; acc1.y += w4.y * x1; acc1.z += w4.z * x1; acc1.w += w4.w * x1;
            acc2.x += w4.x * x2; acc2.y += w4.y * x2; acc2.z += w4.z * x2; acc2.w += w4.w * x2;
            acc3.x += w4.x * x3; acc3.y += w4.y * x3; acc3.z += w4.z * x3; acc3.w += w4.w * x3;
        }

        float4 accs[4] = {acc0, acc1, acc2, acc3};
        #pragma unroll
        for (int rr = 0; rr < 4; ++rr) {
            int row = row0 + tg * 4 + rr;
            if (row < N) {
                float4 o = accs[rr];
                o.x += bias.x; o.y += bias.y; o.z += bias.z; o.w += bias.w;
                *reinterpret_cast<float4*>(s + (size_t)row * H + 4 * tc) = o;
            }
        }
    }
}

// ===========================================================================
// CSR build (once per launch; reused by both layers)
// ===========================================================================
struct EdgeCW { int c; float w; };   // 8 bytes

__global__ __launch_bounds__(256) void zero_kernel(int* __restrict__ p, int n)
{
    int i = blockIdx.x * blockDim.x + threadIdx.x;
    if (i < n) p[i] = 0;
}

__global__ __launch_bounds__(256) void count_kernel(
    const int* __restrict__ erow, int* __restrict__ counts, int E)
{
    int e = blockIdx.x * blockDim.x + threadIdx.x;
    if (e < E) atomicAdd(&counts[erow[e]], 1);
}

#define SCAN_BLK 1024
__global__ __launch_bounds__(SCAN_BLK) void scan_block_kernel(
    const int* __restrict__ counts, int* __restrict__ incl,
    int* __restrict__ bsums, int N)
{
    __shared__ int sm[SCAN_BLK];
    int i = blockIdx.x * SCAN_BLK + threadIdx.x;
    int v = (i < N) ? counts[i] : 0;
    sm[threadIdx.x] = v;
    __syncthreads();
    for (int off = 1; off < SCAN_BLK; off <<= 1) {
        int t = (threadIdx.x >= off) ? sm[threadIdx.x - off] : 0;
        __syncthreads();
        sm[threadIdx.x] += t;
        __syncthreads();
    }
    if (i < N) incl[i] = sm[threadIdx.x];
    if (threadIdx.x == SCAN_BLK - 1) bsums[blockIdx.x] = sm[SCAN_BLK - 1];
}

__global__ void scan_sums_kernel(int* __restrict__ bsums, int nb)
{
    if (blockIdx.x == 0 && threadIdx.x == 0) {
        int run = 0;
        for (int i = 0; i < nb; ++i) { int v = bsums[i]; bsums[i] = run; run += v; }
    }
}

__global__ __launch_bounds__(SCAN_BLK) void finalize_offsets_kernel(
    const int* __restrict__ counts, const int* __restrict__ incl,
    const int* __restrict__ bsums, int* __restrict__ offsets,
    int* __restrict__ cursor, int N, int E)
{
    int i = blockIdx.x * SCAN_BLK + threadIdx.x;
    if (i < N) {
        int start = incl[i] - counts[i] + bsums[blockIdx.x];
        offsets[i] = start;
        cursor[i]  = start;
    }
    if (i == 0) offsets[N] = E;
}

__global__ __launch_bounds__(256) void fill_kernel(
    const int* __restrict__ erow, const int* __restrict__ ecol,
    const float* __restrict__ ew, int* __restrict__ cursor,
    EdgeCW* __restrict__ cw, int E)
{
    int e = blockIdx.x * blockDim.x + threadIdx.x;
    if (e < E) {
        int r = erow[e];
        int pos = atomicAdd(&cursor[r], 1);
        EdgeCW x; x.c = ecol[e]; x.w = ew[e];
        cw[pos] = x;
    }
}

// ===========================================================================
// SpMM (CSR, gather-only) fused with gcn_bias + PReLU.
// One wave per row; lane l owns cols [2l, 2l+1].
// ===========================================================================
__global__ __launch_bounds__(256) void spmm_csr_kernel(
    const int* __restrict__ offsets, const EdgeCW* __restrict__ cw,
    const float* __restrict__ s, const float* __restrict__ gbias,
    const float* __restrict__ a_ptr, float* __restrict__ out, int N)
{
    const float a = a_ptr[0];
    int gid = blockIdx.x * blockDim.x + threadIdx.x;
    int r = gid >> 6;
    int l = gid & 63;
    if (r >= N) return;

    int beg = offsets[r], end = offsets[r + 1];
    float2 acc0 = make_float2(0.f, 0.f);
    float2 acc1 = make_float2(0.f, 0.f);
    int e = beg;
    for (; e + 2 <= end; e += 2) {
        EdgeCW e0 = cw[e];
        EdgeCW e1 = cw[e + 1];
        float2 v0 = *reinterpret_cast<const float2*>(s + (size_t)e0.c * H + l * 2);
        float2 v1 = *reinterpret_cast<const float2*>(s + (size_t)e1.c * H + l * 2);
        acc0.x += e0.w * v0.x; acc0.y += e0.w * v0.y;
        acc1.x += e1.w * v1.x; acc1.y += e1.w * v1.y;
    }
    if (e < end) {
        EdgeCW e0 = cw[e];
        float2 v0 = *reinterpret_cast<const float2*>(s + (size_t)e0.c * H + l * 2);
        acc0.x += e0.w * v0.x; acc0.y += e0.w * v0.y;
    }

    float2 g = *reinterpret_cast<const float2*>(gbias + l * 2);
    float vx = acc0.x + acc1.x + g.x;
    float vy = acc0.y + acc1.y + g.y;
    vx = vx > 0.f ? vx : a * vx;
    vy = vy > 0.f ? vy : a * vy;
    *reinterpret_cast<float2*>(out + (size_t)r * H + l * 2) = make_float2(vx, vy);
}

// ===========================================================================
// Fallback path (round-0): atomic scatter SpMM
// ===========================================================================
__global__ __launch_bounds__(256) void init_out_kernel(
    float* __restrict__ out, const float* __restrict__ gbias, int total4)
{
    int i = blockIdx.x * blockDim.x + threadIdx.x;
    const int stride = gridDim.x * blockDim.x;
    for (; i < total4; i += stride) {
        int c4 = i & 31;
        float4 bv = *reinterpret_cast<const float4*>(gbias + c4 * 4);
        *reinterpret_cast<float4*>(out + (size_t)i * 4) = bv;
    }
}

__global__ __launch_bounds__(256) void spmm_edge_kernel(
    const int* __restrict__ erow, const int* __restrict__ ecol,
    const float* __restrict__ ew, const float* __restrict__ s,
    float* __restrict__ out, int E)
{
    long long gid = (long long)blockIdx.x * blockDim.x + threadIdx.x;
    int e = (int)(gid >> 6);
    int l = (int)(gid & 63);
    if (e >= E) return;
    int r = erow[e];
    int c = ecol[e];
    float w = ew[e];
    float2 v = *reinterpret_cast<const float2*>(s + (size_t)c * H + l * 2);
    unsafeAtomicAdd(out + (size_t)r * H + l * 2 + 0, v.x * w);
    unsafeAtomicAdd(out + (size_t)r * H + l * 2 + 1, v.y * w);
}

__global__ __launch_bounds__(256) void prelu_kernel(
    float* __restrict__ buf, const float* __restrict__ a_ptr, int total4)
{
    const float a = a_ptr[0];
    int i = blockIdx.x * blockDim.x + threadIdx.x;
    const int stride = gridDim.x * blockDim.x;
    for (; i < total4; i += stride) {
        float4 v = *reinterpret_cast<float4*>(buf + (size_t)i * 4);
        v.x = v.x > 0.f ? v.x : a * v.x;
        v.y = v.y > 0.f ? v.y : a * v.y;
        v.z = v.z > 0.f ? v.z : a * v.z;
        v.w = v.w > 0.f ? v.w : a * v.w;
        *reinterpret_cast<float4*>(buf + (size_t)i * 4) = v;
    }
}

// ===========================================================================
extern "C" void kernel_launch(void* const* d_in, const int* in_sizes, int n_in,
                              void* d_out, int out_size, void* d_ws, size_t ws_size,
                              hipStream_t stream)
{
    const float* h        = (const float*)d_in[0];
    const int*   erow     = (const int*)d_in[1];
    const int*   ecol     = (const int*)d_in[2];
    const float* ew       = (const float*)d_in[3];
    const float* fc_w     = (const float*)d_in[4];  // [2][H][H]
    const float* fc_b     = (const float*)d_in[5];  // [2][H]
    const float* gcn_bias = (const float*)d_in[6];  // [2][H]
    const float* prelu_a  = (const float*)d_in[7];  // [2]

    const int N = in_sizes[0] / H;
    const int E = in_sizes[1];
    float* out = (float*)d_out;

    // ---- workspace layout ----
    char* ws = (char*)d_ws;
    float* s = (float*)ws;                 // N*H floats
    size_t off = (size_t)N * H * sizeof(float);
    int* counts  = (int*)(ws + off); off += (size_t)N * 4;
    int* incl    = (int*)(ws + off); off += (size_t)N * 4;
    int* offsets = (int*)(ws + off); off += (size_t)(N + 1) * 4;
    int* cursor  = (int*)(ws + off); off += (size_t)N * 4;
    const int nb_scan = (N + SCAN_BLK - 1) / SCAN_BLK;
    int* bsums   = (int*)(ws + off); off += (size_t)nb_scan * 4;
    off = (off + 7) & ~(size_t)7;          // 8B align
    EdgeCW* cw   = (EdgeCW*)(ws + off); off += (size_t)E * sizeof(EdgeCW);

    const int eblocks = (E + 255) / 256;

    if (off <= ws_size) {
        // ---- CSR build (graph is identical for both layers) ----
        zero_kernel<<<(N + 255) / 256, 256, 0, stream>>>(counts, N);
        count_kernel<<<eblocks, 256, 0, stream>>>(erow, counts, E);
        scan_block_kernel<<<nb_scan, SCAN_BLK, 0, stream>>>(counts, incl, bsums, N);
        scan_sums_kernel<<<1, 64, 0, stream>>>(bsums, nb_scan);
        finalize_offsets_kernel<<<nb_scan, SCAN_BLK, 0, stream>>>(
            counts, incl, bsums, offsets, cursor, N, E);
        fill_kernel<<<eblocks, 256, 0, stream>>>(erow, ecol, ew, cursor, cw, E);

        const int spmm_blocks = (int)(((long long)N * 64 + 255) / 256);

        // ---- layer 0 ----
        gemm_kernel<<<512, GEMM_BLK, 0, stream>>>(h, fc_w, fc_b, s, N);
        spmm_csr_kernel<<<spmm_blocks, 256, 0, stream>>>(
            offsets, cw, s, gcn_bias, prelu_a, out, N);
        // ---- layer 1 ----
        gemm_kernel<<<512, GEMM_BLK, 0, stream>>>(out, fc_w + H * H, fc_b + H, s, N);
        spmm_csr_kernel<<<spmm_blocks, 256, 0, stream>>>(
            offsets, cw, s, gcn_bias + H, prelu_a + 1, out, N);
    } else {
        // ---- fallback: atomic scatter path ----
        const int total4 = N * (H / 4);
        const int spmm_blocks = (int)(((long long)E * 64 + 255) / 256);

        gemm_kernel<<<512, GEMM_BLK, 0, stream>>>(h, fc_w, fc_b, s, N);
        init_out_kernel<<<2048, 256, 0, stream>>>(out, gcn_bias, total4);
        spmm_edge_kernel<<<spmm_blocks, 256, 0, stream>>>(erow, ecol, ew, s, out, E);
        prelu_kernel<<<2048, 256, 0, stream>>>(out, prelu_a, total4);

        gemm_kernel<<<512, GEMM_BLK, 0, stream>>>(out, fc_w + H * H, fc_b + H, s, N);
        init_out_kernel<<<2048, 256, 0, stream>>>(out, gcn_bias + H, total4);
        spmm_edge_kernel<<<spmm_blocks, 256, 0, stream>>>(erow, ecol, ew, s, out, E);
        prelu_kernel<<<2048, 256, 0, stream>>>(out, prelu_a + 1, total4);
    }
}

// Round 3
// 281.690 us; speedup vs baseline: 4.1867x; 1.1605x over previous
//
#include <hip/hip_runtime.h>

#define H 128

typedef __attribute__((ext_vector_type(8))) short bf16x8;
typedef __attribute__((ext_vector_type(4))) short s16x4;
typedef __attribute__((ext_vector_type(4))) float f32x4;

__device__ inline unsigned short f2bf(float f) {
    unsigned u = __float_as_uint(f);
    unsigned r = (u + 0x7fffu + ((u >> 16) & 1u)) >> 16;  // RNE
    return (unsigned short)r;
}

// ===========================================================================
// MFMA GEMM: s[n][j] = sum_k x[n][k]*W[j][k] + b[j]
// 256 thr = 4 waves; block tile 64 rows x 128 cols.
// Wave w: rows (w&1)*32..+31 (2 M-frags), cols (w>>1)*64..+63 (4 N-frags).
// W held as persistent bf16 B-fragments in VGPRs (16 frags, loaded once).
// x staged f32->bf16 in LDS, 272B padded rows (<=2-way banks, free).
// ===========================================================================
#define MB 64

__global__ __launch_bounds__(256) void gemm_mfma_kernel(
    const float* __restrict__ x, const float* __restrict__ W,
    const float* __restrict__ b, float* __restrict__ s, int N, int nbatch)
{
    __shared__ short xlds[MB * 136];   // 136 elems = 272 B per row (16B-aligned)

    const int t = threadIdx.x;
    const int l = t & 63;
    const int w = t >> 6;
    const int row_g = (w & 1) * 32;
    const int col_g = (w >> 1) * 64;
    const int ln15 = l & 15;
    const int lhi  = l >> 4;

    // ---- persistent B-fragments: bw[ks][jt], lane holds W[j][ks*32+lhi*8 ..+7]
    bf16x8 bw[4][4];
    float bias_v[4];
    #pragma unroll
    for (int jt = 0; jt < 4; ++jt) {
        const int j = col_g + jt * 16 + ln15;
        bias_v[jt] = b[j];
        #pragma unroll
        for (int ks = 0; ks < 4; ++ks) {
            const float* p = W + (size_t)j * H + ks * 32 + lhi * 8;
            float4 lo = *reinterpret_cast<const float4*>(p);
            float4 hi = *reinterpret_cast<const float4*>(p + 4);
            bf16x8 f;
            f[0] = (short)f2bf(lo.x); f[1] = (short)f2bf(lo.y);
            f[2] = (short)f2bf(lo.z); f[3] = (short)f2bf(lo.w);
            f[4] = (short)f2bf(hi.x); f[5] = (short)f2bf(hi.y);
            f[6] = (short)f2bf(hi.z); f[7] = (short)f2bf(hi.w);
            bw[ks][jt] = f;
        }
    }

    for (int batch = blockIdx.x; batch < nbatch; batch += gridDim.x) {
        const int row0 = batch * MB;

        __syncthreads();   // protect xlds from previous iteration's readers
        #pragma unroll
        for (int i = 0; i < 8; ++i) {
            int fidx = i * 256 + t;          // 2048 float4 chunks
            int r  = fidx >> 5;              // 32 float4 per row
            int c4 = fidx & 31;
            int gr = row0 + r;
            float4 v = make_float4(0.f, 0.f, 0.f, 0.f);
            if (gr < N) v = *reinterpret_cast<const float4*>(x + (size_t)gr * H + c4 * 4);
            s16x4 p;
            p[0] = (short)f2bf(v.x); p[1] = (short)f2bf(v.y);
            p[2] = (short)f2bf(v.z); p[3] = (short)f2bf(v.w);
            *reinterpret_cast<s16x4*>(&xlds[r * 136 + c4 * 4]) = p;
        }
        __syncthreads();

        f32x4 acc[2][4] = {};
        #pragma unroll
        for (int ks = 0; ks < 4; ++ks) {
            bf16x8 a0 = *reinterpret_cast<const bf16x8*>(
                &xlds[(row_g + ln15) * 136 + ks * 32 + lhi * 8]);
            bf16x8 a1 = *reinterpret_cast<const bf16x8*>(
                &xlds[(row_g + 16 + ln15) * 136 + ks * 32 + lhi * 8]);
            #pragma unroll
            for (int jt = 0; jt < 4; ++jt) {
                acc[0][jt] = __builtin_amdgcn_mfma_f32_16x16x32_bf16(
                    a0, bw[ks][jt], acc[0][jt], 0, 0, 0);
                acc[1][jt] = __builtin_amdgcn_mfma_f32_16x16x32_bf16(
                    a1, bw[ks][jt], acc[1][jt], 0, 0, 0);
            }
        }

        #pragma unroll
        for (int mf = 0; mf < 2; ++mf) {
            const int nbase = row0 + row_g + mf * 16 + lhi * 4;
            #pragma unroll
            for (int jt = 0; jt < 4; ++jt) {
                const int j = col_g + jt * 16 + ln15;
                #pragma unroll
                for (int r = 0; r < 4; ++r) {
                    int n = nbase + r;
                    if (n < N) s[(size_t)n * H + j] = acc[mf][jt][r] + bias_v[jt];
                }
            }
        }
    }
}

// ===========================================================================
// CSR build (once per launch; reused by both layers)
// ===========================================================================
struct EdgeCW { int c; float w; };   // 8 bytes

__global__ __launch_bounds__(256) void zero_kernel(int* __restrict__ p, int n)
{
    int i = blockIdx.x * blockDim.x + threadIdx.x;
    if (i < n) p[i] = 0;
}

__global__ __launch_bounds__(256) void count_kernel(
    const int* __restrict__ erow, int* __restrict__ counts, int E)
{
    int e = blockIdx.x * blockDim.x + threadIdx.x;
    if (e < E) atomicAdd(&counts[erow[e]], 1);
}

#define SCAN_BLK 1024
__global__ __launch_bounds__(SCAN_BLK) void scan_block_kernel(
    const int* __restrict__ counts, int* __restrict__ incl,
    int* __restrict__ bsums, int N)
{
    __shared__ int sm[SCAN_BLK];
    int i = blockIdx.x * SCAN_BLK + threadIdx.x;
    int v = (i < N) ? counts[i] : 0;
    sm[threadIdx.x] = v;
    __syncthreads();
    for (int off = 1; off < SCAN_BLK; off <<= 1) {
        int tv = (threadIdx.x >= off) ? sm[threadIdx.x - off] : 0;
        __syncthreads();
        sm[threadIdx.x] += tv;
        __syncthreads();
    }
    if (i < N) incl[i] = sm[threadIdx.x];
    if (threadIdx.x == SCAN_BLK - 1) bsums[blockIdx.x] = sm[SCAN_BLK - 1];
}

__global__ void scan_sums_kernel(int* __restrict__ bsums, int nb)
{
    if (blockIdx.x == 0 && threadIdx.x == 0) {
        int run = 0;
        for (int i = 0; i < nb; ++i) { int v = bsums[i]; bsums[i] = run; run += v; }
    }
}

__global__ __launch_bounds__(SCAN_BLK) void finalize_offsets_kernel(
    const int* __restrict__ counts, const int* __restrict__ incl,
    const int* __restrict__ bsums, int* __restrict__ offsets,
    int* __restrict__ cursor, int N, int E)
{
    int i = blockIdx.x * SCAN_BLK + threadIdx.x;
    if (i < N) {
        int start = incl[i] - counts[i] + bsums[blockIdx.x];
        offsets[i] = start;
        cursor[i]  = start;
    }
    if (i == 0) offsets[N] = E;
}

__global__ __launch_bounds__(256) void fill_kernel(
    const int* __restrict__ erow, const int* __restrict__ ecol,
    const float* __restrict__ ew, int* __restrict__ cursor,
    EdgeCW* __restrict__ cw, int E)
{
    int e = blockIdx.x * blockDim.x + threadIdx.x;
    if (e < E) {
        int r = erow[e];
        int pos = atomicAdd(&cursor[r], 1);
        EdgeCW x; x.c = ecol[e]; x.w = ew[e];
        cw[pos] = x;
    }
}

// ===========================================================================
// SpMM (CSR, gather-only) fused with gcn_bias + PReLU.
// One wave per row; lane l owns cols [2l, 2l+1].
// ===========================================================================
__global__ __launch_bounds__(256) void spmm_csr_kernel(
    const int* __restrict__ offsets, const EdgeCW* __restrict__ cw,
    const float* __restrict__ s, const float* __restrict__ gbias,
    const float* __restrict__ a_ptr, float* __restrict__ out, int N)
{
    const float a = a_ptr[0];
    int gid = blockIdx.x * blockDim.x + threadIdx.x;
    int r = gid >> 6;
    int l = gid & 63;
    if (r >= N) return;

    int beg = offsets[r], end = offsets[r + 1];
    float2 acc0 = make_float2(0.f, 0.f);
    float2 acc1 = make_float2(0.f, 0.f);
    int e = beg;
    for (; e + 2 <= end; e += 2) {
        EdgeCW e0 = cw[e];
        EdgeCW e1 = cw[e + 1];
        float2 v0 = *reinterpret_cast<const float2*>(s + (size_t)e0.c * H + l * 2);
        float2 v1 = *reinterpret_cast<const float2*>(s + (size_t)e1.c * H + l * 2);
        acc0.x += e0.w * v0.x; acc0.y += e0.w * v0.y;
        acc1.x += e1.w * v1.x; acc1.y += e1.w * v1.y;
    }
    if (e < end) {
        EdgeCW e0 = cw[e];
        float2 v0 = *reinterpret_cast<const float2*>(s + (size_t)e0.c * H + l * 2);
        acc0.x += e0.w * v0.x; acc0.y += e0.w * v0.y;
    }

    float2 g = *reinterpret_cast<const float2*>(gbias + l * 2);
    float vx = acc0.x + acc1.x + g.x;
    float vy = acc0.y + acc1.y + g.y;
    vx = vx > 0.f ? vx : a * vx;
    vy = vy > 0.f ? vy : a * vy;
    *reinterpret_cast<float2*>(out + (size_t)r * H + l * 2) = make_float2(vx, vy);
}

// ===========================================================================
// Fallback path: atomic scatter SpMM (used only if ws too small)
// ===========================================================================
__global__ __launch_bounds__(256) void init_out_kernel(
    float* __restrict__ out, const float* __restrict__ gbias, int total4)
{
    int i = blockIdx.x * blockDim.x + threadIdx.x;
    const int stride = gridDim.x * blockDim.x;
    for (; i < total4; i += stride) {
        int c4 = i & 31;
        float4 bv = *reinterpret_cast<const float4*>(gbias + c4 * 4);
        *reinterpret_cast<float4*>(out + (size_t)i * 4) = bv;
    }
}

__global__ __launch_bounds__(256) void spmm_edge_kernel(
    const int* __restrict__ erow, const int* __restrict__ ecol,
    const float* __restrict__ ew, const float* __restrict__ s,
    float* __restrict__ out, int E)
{
    long long gid = (long long)blockIdx.x * blockDim.x + threadIdx.x;
    int e = (int)(gid >> 6);
    int l = (int)(gid & 63);
    if (e >= E) return;
    int r = erow[e];
    int c = ecol[e];
    float w = ew[e];
    float2 v = *reinterpret_cast<const float2*>(s + (size_t)c * H + l * 2);
    unsafeAtomicAdd(out + (size_t)r * H + l * 2 + 0, v.x * w);
    unsafeAtomicAdd(out + (size_t)r * H + l * 2 + 1, v.y * w);
}

__global__ __launch_bounds__(256) void prelu_kernel(
    float* __restrict__ buf, const float* __restrict__ a_ptr, int total4)
{
    const float a = a_ptr[0];
    int i = blockIdx.x * blockDim.x + threadIdx.x;
    const int stride = gridDim.x * blockDim.x;
    for (; i < total4; i += stride) {
        float4 v = *reinterpret_cast<float4*>(buf + (size_t)i * 4);
        v.x = v.x > 0.f ? v.x : a * v.x;
        v.y = v.y > 0.f ? v.y : a * v.y;
        v.z = v.z > 0.f ? v.z : a * v.z;
        v.w = v.w > 0.f ? v.w : a * v.w;
        *reinterpret_cast<float4*>(buf + (size_t)i * 4) = v;
    }
}

// ===========================================================================
extern "C" void kernel_launch(void* const* d_in, const int* in_sizes, int n_in,
                              void* d_out, int out_size, void* d_ws, size_t ws_size,
                              hipStream_t stream)
{
    const float* h        = (const float*)d_in[0];
    const int*   erow     = (const int*)d_in[1];
    const int*   ecol     = (const int*)d_in[2];
    const float* ew       = (const float*)d_in[3];
    const float* fc_w     = (const float*)d_in[4];  // [2][H][H]
    const float* fc_b     = (const float*)d_in[5];  // [2][H]
    const float* gcn_bias = (const float*)d_in[6];  // [2][H]
    const float* prelu_a  = (const float*)d_in[7];  // [2]

    const int N = in_sizes[0] / H;
    const int E = in_sizes[1];
    float* out = (float*)d_out;

    // ---- workspace layout ----
    char* ws = (char*)d_ws;
    float* s = (float*)ws;                 // N*H floats
    size_t off = (size_t)N * H * sizeof(float);
    int* counts  = (int*)(ws + off); off += (size_t)N * 4;
    int* incl    = (int*)(ws + off); off += (size_t)N * 4;
    int* offsets = (int*)(ws + off); off += (size_t)(N + 1) * 4;
    int* cursor  = (int*)(ws + off); off += (size_t)N * 4;
    const int nb_scan = (N + SCAN_BLK - 1) / SCAN_BLK;
    int* bsums   = (int*)(ws + off); off += (size_t)nb_scan * 4;
    off = (off + 7) & ~(size_t)7;
    EdgeCW* cw   = (EdgeCW*)(ws + off); off += (size_t)E * sizeof(EdgeCW);

    const int eblocks = (E + 255) / 256;
    const int nbatch = (N + MB - 1) / MB;

    if (off <= ws_size) {
        // ---- CSR build (graph identical for both layers) ----
        zero_kernel<<<(N + 255) / 256, 256, 0, stream>>>(counts, N);
        count_kernel<<<eblocks, 256, 0, stream>>>(erow, counts, E);
        scan_block_kernel<<<nb_scan, SCAN_BLK, 0, stream>>>(counts, incl, bsums, N);
        scan_sums_kernel<<<1, 64, 0, stream>>>(bsums, nb_scan);
        finalize_offsets_kernel<<<nb_scan, SCAN_BLK, 0, stream>>>(
            counts, incl, bsums, offsets, cursor, N, E);
        fill_kernel<<<eblocks, 256, 0, stream>>>(erow, ecol, ew, cursor, cw, E);

        const int spmm_blocks = (int)(((long long)N * 64 + 255) / 256);

        // ---- layer 0 ----
        gemm_mfma_kernel<<<nbatch, 256, 0, stream>>>(h, fc_w, fc_b, s, N, nbatch);
        spmm_csr_kernel<<<spmm_blocks, 256, 0, stream>>>(
            offsets, cw, s, gcn_bias, prelu_a, out, N);
        // ---- layer 1 ----
        gemm_mfma_kernel<<<nbatch, 256, 0, stream>>>(out, fc_w + H * H, fc_b + H, s, N, nbatch);
        spmm_csr_kernel<<<spmm_blocks, 256, 0, stream>>>(
            offsets, cw, s, gcn_bias + H, prelu_a + 1, out, N);
    } else {
        // ---- fallback: atomic scatter path ----
        const int total4 = N * (H / 4);
        const int spmm_blocks = (int)(((long long)E * 64 + 255) / 256);

        gemm_mfma_kernel<<<nbatch, 256, 0, stream>>>(h, fc_w, fc_b, s, N, nbatch);
        init_out_kernel<<<2048, 256, 0, stream>>>(out, gcn_bias, total4);
        spmm_edge_kernel<<<spmm_blocks, 256, 0, stream>>>(erow, ecol, ew, s, out, E);
        prelu_kernel<<<2048, 256, 0, stream>>>(out, prelu_a, total4);

        gemm_mfma_kernel<<<nbatch, 256, 0, stream>>>(out, fc_w + H * H, fc_b + H, s, N, nbatch);
        init_out_kernel<<<2048, 256, 0, stream>>>(out, gcn_bias + H, total4);
        spmm_edge_kernel<<<spmm_blocks, 256, 0, stream>>>(erow, ecol, ew, s, out, E);
        prelu_kernel<<<2048, 256, 0, stream>>>(out, prelu_a + 1, total4);
    }
}

// Round 4
// 254.406 us; speedup vs baseline: 4.6357x; 1.1072x over previous
//
#include <hip/hip_runtime.h>

#define H 128

typedef __attribute__((ext_vector_type(8))) short bf16x8;
typedef __attribute__((ext_vector_type(4))) short s16x4;
typedef __attribute__((ext_vector_type(4))) float f32x4;

__device__ inline unsigned short f2bf(float f) {
    unsigned u = __float_as_uint(f);
    unsigned r = (u + 0x7fffu + ((u >> 16) & 1u)) >> 16;  // RNE
    return (unsigned short)r;
}
__device__ inline float bflo(unsigned u) { return __uint_as_float(u << 16); }
__device__ inline float bfhi(unsigned u) { return __uint_as_float(u & 0xffff0000u); }

// ===========================================================================
// MFMA GEMM: s_bf[n][j] = bf16( sum_k x[n][k]*W[j][k] + b[j] )
// 256 thr = 4 waves; block tile 64 rows x 128 cols.
// W held as persistent bf16 B-fragments in VGPRs (loaded once per block).
// A staged into LDS (f32->bf16 convert if BF16IN=false), 272B padded rows.
// ===========================================================================
#define MB 64

template<bool BF16IN>
__global__ __launch_bounds__(256) void gemm_mfma_kernel(
    const void* __restrict__ xv, const float* __restrict__ W,
    const float* __restrict__ b, short* __restrict__ s_out, int N, int nbatch)
{
    __shared__ short xlds[MB * 136];   // 136 shorts = 272 B per row

    const int t = threadIdx.x;
    const int l = t & 63;
    const int w = t >> 6;
    const int row_g = (w & 1) * 32;
    const int col_g = (w >> 1) * 64;
    const int ln15 = l & 15;
    const int lhi  = l >> 4;

    bf16x8 bw[4][4];
    float bias_v[4];
    #pragma unroll
    for (int jt = 0; jt < 4; ++jt) {
        const int j = col_g + jt * 16 + ln15;
        bias_v[jt] = b[j];
        #pragma unroll
        for (int ks = 0; ks < 4; ++ks) {
            const float* p = W + (size_t)j * H + ks * 32 + lhi * 8;
            float4 lo = *reinterpret_cast<const float4*>(p);
            float4 hi = *reinterpret_cast<const float4*>(p + 4);
            bf16x8 f;
            f[0] = (short)f2bf(lo.x); f[1] = (short)f2bf(lo.y);
            f[2] = (short)f2bf(lo.z); f[3] = (short)f2bf(lo.w);
            f[4] = (short)f2bf(hi.x); f[5] = (short)f2bf(hi.y);
            f[6] = (short)f2bf(hi.z); f[7] = (short)f2bf(hi.w);
            bw[ks][jt] = f;
        }
    }

    for (int batch = blockIdx.x; batch < nbatch; batch += gridDim.x) {
        const int row0 = batch * MB;

        __syncthreads();
        #pragma unroll
        for (int i = 0; i < 8; ++i) {
            int fidx = i * 256 + t;          // 2048 chunks of 4 elems
            int r  = fidx >> 5;
            int c4 = fidx & 31;
            int gr = row0 + r;
            s16x4 p = {0, 0, 0, 0};
            if (gr < N) {
                if (BF16IN) {
                    p = *reinterpret_cast<const s16x4*>(
                        (const short*)xv + (size_t)gr * H + c4 * 4);
                } else {
                    float4 v = *reinterpret_cast<const float4*>(
                        (const float*)xv + (size_t)gr * H + c4 * 4);
                    p[0] = (short)f2bf(v.x); p[1] = (short)f2bf(v.y);
                    p[2] = (short)f2bf(v.z); p[3] = (short)f2bf(v.w);
                }
            }
            *reinterpret_cast<s16x4*>(&xlds[r * 136 + c4 * 4]) = p;
        }
        __syncthreads();

        f32x4 acc[2][4] = {};
        #pragma unroll
        for (int ks = 0; ks < 4; ++ks) {
            bf16x8 a0 = *reinterpret_cast<const bf16x8*>(
                &xlds[(row_g + ln15) * 136 + ks * 32 + lhi * 8]);
            bf16x8 a1 = *reinterpret_cast<const bf16x8*>(
                &xlds[(row_g + 16 + ln15) * 136 + ks * 32 + lhi * 8]);
            #pragma unroll
            for (int jt = 0; jt < 4; ++jt) {
                acc[0][jt] = __builtin_amdgcn_mfma_f32_16x16x32_bf16(
                    a0, bw[ks][jt], acc[0][jt], 0, 0, 0);
                acc[1][jt] = __builtin_amdgcn_mfma_f32_16x16x32_bf16(
                    a1, bw[ks][jt], acc[1][jt], 0, 0, 0);
            }
        }

        #pragma unroll
        for (int mf = 0; mf < 2; ++mf) {
            const int nbase = row0 + row_g + mf * 16 + lhi * 4;
            #pragma unroll
            for (int jt = 0; jt < 4; ++jt) {
                const int j = col_g + jt * 16 + ln15;
                #pragma unroll
                for (int r = 0; r < 4; ++r) {
                    int n = nbase + r;
                    if (n < N)
                        s_out[(size_t)n * H + j] = (short)f2bf(acc[mf][jt][r] + bias_v[jt]);
                }
            }
        }
    }
}

// ===========================================================================
// CSR build (once per launch; graph identical for both layers)
// ===========================================================================
struct EdgeCW { int c; float w; };   // 8 bytes

__global__ __launch_bounds__(256) void zero_kernel(int* __restrict__ p, int n)
{
    int i = blockIdx.x * blockDim.x + threadIdx.x;
    if (i < n) p[i] = 0;
}

__global__ __launch_bounds__(256) void count_kernel(
    const int* __restrict__ erow, int* __restrict__ counts, int E)
{
    int e = blockIdx.x * blockDim.x + threadIdx.x;
    if (e < E) atomicAdd(&counts[erow[e]], 1);
}

#define SCAN_BLK 1024
__global__ __launch_bounds__(SCAN_BLK) void scan_block_kernel(
    const int* __restrict__ counts, int* __restrict__ incl,
    int* __restrict__ bsums, int N)
{
    __shared__ int sm[SCAN_BLK];
    int i = blockIdx.x * SCAN_BLK + threadIdx.x;
    int v = (i < N) ? counts[i] : 0;
    sm[threadIdx.x] = v;
    __syncthreads();
    for (int off = 1; off < SCAN_BLK; off <<= 1) {
        int tv = (threadIdx.x >= off) ? sm[threadIdx.x - off] : 0;
        __syncthreads();
        sm[threadIdx.x] += tv;
        __syncthreads();
    }
    if (i < N) incl[i] = sm[threadIdx.x];
    if (threadIdx.x == SCAN_BLK - 1) bsums[blockIdx.x] = sm[SCAN_BLK - 1];
}

// single block: parallel exclusive scan of bsums (nb <= SCAN_BLK)
__global__ __launch_bounds__(SCAN_BLK) void scan_sums_kernel(int* __restrict__ bsums, int nb)
{
    __shared__ int sm[SCAN_BLK];
    if (nb <= SCAN_BLK) {
        int i = threadIdx.x;
        int v = (i < nb) ? bsums[i] : 0;
        sm[i] = v;
        __syncthreads();
        for (int off = 1; off < SCAN_BLK; off <<= 1) {
            int tv = (i >= off) ? sm[i - off] : 0;
            __syncthreads();
            sm[i] += tv;
            __syncthreads();
        }
        if (i < nb) bsums[i] = sm[i] - v;   // exclusive
    } else if (threadIdx.x == 0) {
        int run = 0;
        for (int i = 0; i < nb; ++i) { int v = bsums[i]; bsums[i] = run; run += v; }
    }
}

__global__ __launch_bounds__(SCAN_BLK) void finalize_offsets_kernel(
    const int* __restrict__ counts, const int* __restrict__ incl,
    const int* __restrict__ bsums, int* __restrict__ offsets,
    int* __restrict__ cursor, int N, int E)
{
    int i = blockIdx.x * SCAN_BLK + threadIdx.x;
    if (i < N) {
        int start = incl[i] - counts[i] + bsums[blockIdx.x];
        offsets[i] = start;
        cursor[i]  = start;
    }
    if (i == 0) offsets[N] = E;
}

__global__ __launch_bounds__(256) void fill_kernel(
    const int* __restrict__ erow, const int* __restrict__ ecol,
    const float* __restrict__ ew, int* __restrict__ cursor,
    EdgeCW* __restrict__ cw, int E)
{
    int e = blockIdx.x * blockDim.x + threadIdx.x;
    if (e < E) {
        int r = erow[e];
        int pos = atomicAdd(&cursor[r], 1);
        EdgeCW x; x.c = ecol[e]; x.w = ew[e];
        cw[pos] = x;
    }
}

// ===========================================================================
// SpMM (CSR, gather-only, bf16 s) fused with gcn_bias + PReLU.
// One wave per row; lane l owns cols [2l, 2l+1] (u32 load = 2 bf16).
// MODE: 0 = write f32 out, 1 = write bf16 out, 2 = write both.
// ===========================================================================
template<int MODE>
__global__ __launch_bounds__(256) void spmm_csr_kernel(
    const int* __restrict__ offsets, const EdgeCW* __restrict__ cw,
    const short* __restrict__ s_bf, const float* __restrict__ gbias,
    const float* __restrict__ a_ptr, float* __restrict__ out_f,
    short* __restrict__ out_b, int N)
{
    const float a = a_ptr[0];
    int gid = blockIdx.x * blockDim.x + threadIdx.x;
    int r = gid >> 6;
    int l = gid & 63;
    if (r >= N) return;

    int beg = offsets[r], end = offsets[r + 1];
    float2 acc0 = make_float2(0.f, 0.f), acc1 = acc0, acc2 = acc0, acc3 = acc0;
    int e = beg;
    for (; e + 4 <= end; e += 4) {
        EdgeCW e0 = cw[e],     e1 = cw[e + 1];
        EdgeCW e2 = cw[e + 2], e3 = cw[e + 3];
        unsigned u0 = *reinterpret_cast<const unsigned*>(s_bf + (size_t)e0.c * H + 2 * l);
        unsigned u1 = *reinterpret_cast<const unsigned*>(s_bf + (size_t)e1.c * H + 2 * l);
        unsigned u2 = *reinterpret_cast<const unsigned*>(s_bf + (size_t)e2.c * H + 2 * l);
        unsigned u3 = *reinterpret_cast<const unsigned*>(s_bf + (size_t)e3.c * H + 2 * l);
        acc0.x += e0.w * bflo(u0); acc0.y += e0.w * bfhi(u0);
        acc1.x += e1.w * bflo(u1); acc1.y += e1.w * bfhi(u1);
        acc2.x += e2.w * bflo(u2); acc2.y += e2.w * bfhi(u2);
        acc3.x += e3.w * bflo(u3); acc3.y += e3.w * bfhi(u3);
    }
    for (; e < end; ++e) {
        EdgeCW e0 = cw[e];
        unsigned u0 = *reinterpret_cast<const unsigned*>(s_bf + (size_t)e0.c * H + 2 * l);
        acc0.x += e0.w * bflo(u0); acc0.y += e0.w * bfhi(u0);
    }

    float2 g = *reinterpret_cast<const float2*>(gbias + l * 2);
    float vx = (acc0.x + acc1.x) + (acc2.x + acc3.x) + g.x;
    float vy = (acc0.y + acc1.y) + (acc2.y + acc3.y) + g.y;
    vx = vx > 0.f ? vx : a * vx;
    vy = vy > 0.f ? vy : a * vy;

    if (MODE == 0 || MODE == 2)
        *reinterpret_cast<float2*>(out_f + (size_t)r * H + l * 2) = make_float2(vx, vy);
    if (MODE == 1 || MODE == 2) {
        unsigned pack = (unsigned)f2bf(vx) | ((unsigned)f2bf(vy) << 16);
        *reinterpret_cast<unsigned*>(out_b + (size_t)r * H + l * 2) = pack;
    }
}

// ===========================================================================
// Fallback path (ws too small for CSR): atomic scatter SpMM over bf16 s
// ===========================================================================
__global__ __launch_bounds__(256) void init_out_kernel(
    float* __restrict__ out, const float* __restrict__ gbias, int total4)
{
    int i = blockIdx.x * blockDim.x + threadIdx.x;
    const int stride = gridDim.x * blockDim.x;
    for (; i < total4; i += stride) {
        int c4 = i & 31;
        float4 bv = *reinterpret_cast<const float4*>(gbias + c4 * 4);
        *reinterpret_cast<float4*>(out + (size_t)i * 4) = bv;
    }
}

__global__ __launch_bounds__(256) void spmm_edge_kernel(
    const int* __restrict__ erow, const int* __restrict__ ecol,
    const float* __restrict__ ew, const short* __restrict__ s_bf,
    float* __restrict__ out, int E)
{
    long long gid = (long long)blockIdx.x * blockDim.x + threadIdx.x;
    int e = (int)(gid >> 6);
    int l = (int)(gid & 63);
    if (e >= E) return;
    int r = erow[e];
    int c = ecol[e];
    float w = ew[e];
    unsigned u = *reinterpret_cast<const unsigned*>(s_bf + (size_t)c * H + 2 * l);
    unsafeAtomicAdd(out + (size_t)r * H + l * 2 + 0, bflo(u) * w);
    unsafeAtomicAdd(out + (size_t)r * H + l * 2 + 1, bfhi(u) * w);
}

__global__ __launch_bounds__(256) void prelu_kernel(
    float* __restrict__ buf, const float* __restrict__ a_ptr, int total4)
{
    const float a = a_ptr[0];
    int i = blockIdx.x * blockDim.x + threadIdx.x;
    const int stride = gridDim.x * blockDim.x;
    for (; i < total4; i += stride) {
        float4 v = *reinterpret_cast<float4*>(buf + (size_t)i * 4);
        v.x = v.x > 0.f ? v.x : a * v.x;
        v.y = v.y > 0.f ? v.y : a * v.y;
        v.z = v.z > 0.f ? v.z : a * v.z;
        v.w = v.w > 0.f ? v.w : a * v.w;
        *reinterpret_cast<float4*>(buf + (size_t)i * 4) = v;
    }
}

// ===========================================================================
extern "C" void kernel_launch(void* const* d_in, const int* in_sizes, int n_in,
                              void* d_out, int out_size, void* d_ws, size_t ws_size,
                              hipStream_t stream)
{
    const float* h        = (const float*)d_in[0];
    const int*   erow     = (const int*)d_in[1];
    const int*   ecol     = (const int*)d_in[2];
    const float* ew       = (const float*)d_in[3];
    const float* fc_w     = (const float*)d_in[4];  // [2][H][H]
    const float* fc_b     = (const float*)d_in[5];  // [2][H]
    const float* gcn_bias = (const float*)d_in[6];  // [2][H]
    const float* prelu_a  = (const float*)d_in[7];  // [2]

    const int N = in_sizes[0] / H;
    const int E = in_sizes[1];
    float* out = (float*)d_out;

    // ---- workspace layout ----
    char* ws = (char*)d_ws;
    short* s_bf  = (short*)ws;                       // N*H bf16 (GEMM out / spmm in)
    size_t off = (size_t)N * H * sizeof(short);
    short* x1_bf = (short*)(ws + off); off += (size_t)N * H * sizeof(short);
    int* counts  = (int*)(ws + off); off += (size_t)N * 4;
    int* incl    = (int*)(ws + off); off += (size_t)N * 4;
    int* offsets = (int*)(ws + off); off += (size_t)(N + 1) * 4;
    int* cursor  = (int*)(ws + off); off += (size_t)N * 4;
    const int nb_scan = (N + SCAN_BLK - 1) / SCAN_BLK;
    int* bsums   = (int*)(ws + off); off += (size_t)nb_scan * 4;
    off = (off + 7) & ~(size_t)7;
    EdgeCW* cw   = (EdgeCW*)(ws + off); off += (size_t)E * sizeof(EdgeCW);

    const int eblocks = (E + 255) / 256;
    const int nbatch = (N + MB - 1) / MB;

    if (off <= ws_size) {
        // ---- CSR build ----
        zero_kernel<<<(N + 255) / 256, 256, 0, stream>>>(counts, N);
        count_kernel<<<eblocks, 256, 0, stream>>>(erow, counts, E);
        scan_block_kernel<<<nb_scan, SCAN_BLK, 0, stream>>>(counts, incl, bsums, N);
        scan_sums_kernel<<<1, SCAN_BLK, 0, stream>>>(bsums, nb_scan);
        finalize_offsets_kernel<<<nb_scan, SCAN_BLK, 0, stream>>>(
            counts, incl, bsums, offsets, cursor, N, E);
        fill_kernel<<<eblocks, 256, 0, stream>>>(erow, ecol, ew, cursor, cw, E);

        const int spmm_blocks = (int)(((long long)N * 64 + 255) / 256);

        // ---- layer 0 ----  (activation kept bf16-only: feeds GEMM-1 A input)
        gemm_mfma_kernel<false><<<nbatch, 256, 0, stream>>>(h, fc_w, fc_b, s_bf, N, nbatch);
        spmm_csr_kernel<1><<<spmm_blocks, 256, 0, stream>>>(
            offsets, cw, s_bf, gcn_bias, prelu_a, nullptr, x1_bf, N);
        // ---- layer 1 ----
        gemm_mfma_kernel<true><<<nbatch, 256, 0, stream>>>(x1_bf, fc_w + H * H, fc_b + H, s_bf, N, nbatch);
        spmm_csr_kernel<0><<<spmm_blocks, 256, 0, stream>>>(
            offsets, cw, s_bf, gcn_bias + H, prelu_a + 1, out, nullptr, N);
    } else {
        // ---- fallback: atomic scatter path (needs only s_bf = N*H*2 bytes) ----
        const int total4 = N * (H / 4);
        const int spmm_blocks = (int)(((long long)E * 64 + 255) / 256);

        gemm_mfma_kernel<false><<<nbatch, 256, 0, stream>>>(h, fc_w, fc_b, s_bf, N, nbatch);
        init_out_kernel<<<2048, 256, 0, stream>>>(out, gcn_bias, total4);
        spmm_edge_kernel<<<spmm_blocks, 256, 0, stream>>>(erow, ecol, ew, s_bf, out, E);
        prelu_kernel<<<2048, 256, 0, stream>>>(out, prelu_a, total4);

        gemm_mfma_kernel<false><<<nbatch, 256, 0, stream>>>(out, fc_w + H * H, fc_b + H, s_bf, N, nbatch);
        init_out_kernel<<<2048, 256, 0, stream>>>(out, gcn_bias + H, total4);
        spmm_edge_kernel<<<spmm_blocks, 256, 0, stream>>>(erow, ecol, ew, s_bf, out, E);
        prelu_kernel<<<2048, 256, 0, stream>>>(out, prelu_a + 1, total4);
    }
}

// Round 5
// 204.668 us; speedup vs baseline: 5.7623x; 1.2430x over previous
//
#include <hip/hip_runtime.h>

#define H 128

typedef __attribute__((ext_vector_type(8))) short bf16x8;
typedef __attribute__((ext_vector_type(4))) short s16x4;
typedef __attribute__((ext_vector_type(4))) float f32x4;

__device__ inline unsigned short f2bf(float f) {
    unsigned u = __float_as_uint(f);
    unsigned r = (u + 0x7fffu + ((u >> 16) & 1u)) >> 16;  // RNE
    return (unsigned short)r;
}
__device__ inline float bflo(unsigned u) { return __uint_as_float(u << 16); }
__device__ inline float bfhi(unsigned u) { return __uint_as_float(u & 0xffff0000u); }

// ===========================================================================
// MFMA GEMM v3: s_bf[n][j] = bf16( sum_k x[n][k]*W[j][k] + b[j] )
// 256 thr = 4 waves, persistent grid. W staged bf16 in LDS (padded rows,
// 34 KB) ONCE per block; x fragments direct global->VGPR (no staging, no
// per-batch barriers). Operand-swapped MFMA: D lanes = n, regs = j, so the
// epilogue stores 8 B (4 bf16 cols) per frag.
// Wave w: rows n_g=(w&1)*32 (2 n-frags), cols col_g=(w>>1)*64 (4 j-frags).
// ===========================================================================
#define MB 64

template<bool BF16IN>
__global__ __launch_bounds__(256) void gemm_mfma_kernel(
    const void* __restrict__ xv, const float* __restrict__ W,
    const float* __restrict__ b, short* __restrict__ s_out, int N, int nbatch)
{
    __shared__ short wlds[H * 136];   // 34816 B, 272 B padded rows

    const int t = threadIdx.x;
    const int l = t & 63;
    const int w = t >> 6;
    const int n_g   = (w & 1) * 32;
    const int col_g = (w >> 1) * 64;
    const int ln15 = l & 15;
    const int lhi  = l >> 4;

    // ---- stage W -> LDS (coalesced f32 read, bf16 write), once per block
    #pragma unroll
    for (int i = 0; i < 16; ++i) {
        int fidx = i * 256 + t;          // 4096 float4 chunks
        int j  = fidx >> 5;              // 32 float4 per W row
        int c4 = fidx & 31;
        float4 v = *reinterpret_cast<const float4*>(W + (size_t)j * H + c4 * 4);
        s16x4 p;
        p[0] = (short)f2bf(v.x); p[1] = (short)f2bf(v.y);
        p[2] = (short)f2bf(v.z); p[3] = (short)f2bf(v.w);
        *reinterpret_cast<s16x4*>(&wlds[j * 136 + c4 * 4]) = p;
    }

    // bias: float4 covers regs r=0..3 at j = col_g + jt*16 + lhi*4
    float4 bias4[4];
    #pragma unroll
    for (int jt = 0; jt < 4; ++jt)
        bias4[jt] = *reinterpret_cast<const float4*>(b + col_g + jt * 16 + lhi * 4);

    __syncthreads();   // wlds ready; read-only hereafter (no more barriers)

    for (int batch = blockIdx.x; batch < nbatch; batch += gridDim.x) {
        const int row0 = batch * MB;

        // ---- x fragments: ax[ks][nf], lane holds x[n][ks*32+lhi*8 ..+7]
        bf16x8 ax[4][2];
        #pragma unroll
        for (int nf = 0; nf < 2; ++nf) {
            const int n = row0 + n_g + nf * 16 + ln15;
            const bool ok = (n < N);
            #pragma unroll
            for (int ks = 0; ks < 4; ++ks) {
                bf16x8 f = {0, 0, 0, 0, 0, 0, 0, 0};
                if (ok) {
                    if (BF16IN) {
                        f = *reinterpret_cast<const bf16x8*>(
                            (const short*)xv + (size_t)n * H + ks * 32 + lhi * 8);
                    } else {
                        const float* p = (const float*)xv + (size_t)n * H + ks * 32 + lhi * 8;
                        float4 lo = *reinterpret_cast<const float4*>(p);
                        float4 hi = *reinterpret_cast<const float4*>(p + 4);
                        f[0] = (short)f2bf(lo.x); f[1] = (short)f2bf(lo.y);
                        f[2] = (short)f2bf(lo.z); f[3] = (short)f2bf(lo.w);
                        f[4] = (short)f2bf(hi.x); f[5] = (short)f2bf(hi.y);
                        f[6] = (short)f2bf(hi.z); f[7] = (short)f2bf(hi.w);
                    }
                }
                ax[ks][nf] = f;
            }
        }

        // ---- MFMA: D = W_frag x x_frag  (lanes = n, regs = j)
        f32x4 acc[2][4] = {};
        #pragma unroll
        for (int ks = 0; ks < 4; ++ks) {
            #pragma unroll
            for (int jt = 0; jt < 4; ++jt) {
                bf16x8 aw = *reinterpret_cast<const bf16x8*>(
                    &wlds[(col_g + jt * 16 + ln15) * 136 + ks * 32 + lhi * 8]);
                acc[0][jt] = __builtin_amdgcn_mfma_f32_16x16x32_bf16(
                    aw, ax[ks][0], acc[0][jt], 0, 0, 0);
                acc[1][jt] = __builtin_amdgcn_mfma_f32_16x16x32_bf16(
                    aw, ax[ks][1], acc[1][jt], 0, 0, 0);
            }
        }

        // ---- epilogue: 4 bf16 cols packed per 8 B store
        #pragma unroll
        for (int nf = 0; nf < 2; ++nf) {
            const int n = row0 + n_g + nf * 16 + ln15;
            if (n < N) {
                #pragma unroll
                for (int jt = 0; jt < 4; ++jt) {
                    s16x4 p;
                    p[0] = (short)f2bf(acc[nf][jt][0] + bias4[jt].x);
                    p[1] = (short)f2bf(acc[nf][jt][1] + bias4[jt].y);
                    p[2] = (short)f2bf(acc[nf][jt][2] + bias4[jt].z);
                    p[3] = (short)f2bf(acc[nf][jt][3] + bias4[jt].w);
                    *reinterpret_cast<s16x4*>(
                        s_out + (size_t)n * H + col_g + jt * 16 + lhi * 4) = p;
                }
            }
        }
    }
}

// ===========================================================================
// CSR build (once per launch; graph identical for both layers)
// ===========================================================================
struct EdgeCW { int c; float w; };   // 8 bytes

__global__ __launch_bounds__(256) void zero_kernel(int* __restrict__ p, int n)
{
    int i = blockIdx.x * blockDim.x + threadIdx.x;
    if (i < n) p[i] = 0;
}

__global__ __launch_bounds__(256) void count_kernel(
    const int* __restrict__ erow, int* __restrict__ counts, int E)
{
    int e = blockIdx.x * blockDim.x + threadIdx.x;
    if (e < E) atomicAdd(&counts[erow[e]], 1);
}

#define SCAN_BLK 1024
__global__ __launch_bounds__(SCAN_BLK) void scan_block_kernel(
    const int* __restrict__ counts, int* __restrict__ incl,
    int* __restrict__ bsums, int N)
{
    __shared__ int sm[SCAN_BLK];
    int i = blockIdx.x * SCAN_BLK + threadIdx.x;
    int v = (i < N) ? counts[i] : 0;
    sm[threadIdx.x] = v;
    __syncthreads();
    for (int off = 1; off < SCAN_BLK; off <<= 1) {
        int tv = (threadIdx.x >= off) ? sm[threadIdx.x - off] : 0;
        __syncthreads();
        sm[threadIdx.x] += tv;
        __syncthreads();
    }
    if (i < N) incl[i] = sm[threadIdx.x];
    if (threadIdx.x == SCAN_BLK - 1) bsums[blockIdx.x] = sm[SCAN_BLK - 1];
}

__global__ __launch_bounds__(SCAN_BLK) void scan_sums_kernel(int* __restrict__ bsums, int nb)
{
    __shared__ int sm[SCAN_BLK];
    if (nb <= SCAN_BLK) {
        int i = threadIdx.x;
        int v = (i < nb) ? bsums[i] : 0;
        sm[i] = v;
        __syncthreads();
        for (int off = 1; off < SCAN_BLK; off <<= 1) {
            int tv = (i >= off) ? sm[i - off] : 0;
            __syncthreads();
            sm[i] += tv;
            __syncthreads();
        }
        if (i < nb) bsums[i] = sm[i] - v;   // exclusive
    } else if (threadIdx.x == 0) {
        int run = 0;
        for (int i = 0; i < nb; ++i) { int v = bsums[i]; bsums[i] = run; run += v; }
    }
}

__global__ __launch_bounds__(SCAN_BLK) void finalize_offsets_kernel(
    const int* __restrict__ counts, const int* __restrict__ incl,
    const int* __restrict__ bsums, int* __restrict__ offsets,
    int* __restrict__ cursor, int N, int E)
{
    int i = blockIdx.x * SCAN_BLK + threadIdx.x;
    if (i < N) {
        int start = incl[i] - counts[i] + bsums[blockIdx.x];
        offsets[i] = start;
        cursor[i]  = start;
    }
    if (i == 0) offsets[N] = E;
}

__global__ __launch_bounds__(256) void fill_kernel(
    const int* __restrict__ erow, const int* __restrict__ ecol,
    const float* __restrict__ ew, int* __restrict__ cursor,
    EdgeCW* __restrict__ cw, int E)
{
    int e = blockIdx.x * blockDim.x + threadIdx.x;
    if (e < E) {
        int r = erow[e];
        int pos = atomicAdd(&cursor[r], 1);
        EdgeCW x; x.c = ecol[e]; x.w = ew[e];
        cw[pos] = x;
    }
}

// ===========================================================================
// SpMM (CSR, gather-only, bf16 s) fused with gcn_bias + PReLU.
// One wave per row; lane l owns cols [2l, 2l+1] (u32 load = 2 bf16).
// MODE: 0 = write f32 out, 1 = write bf16 out.
// ===========================================================================
template<int MODE>
__global__ __launch_bounds__(256) void spmm_csr_kernel(
    const int* __restrict__ offsets, const EdgeCW* __restrict__ cw,
    const short* __restrict__ s_bf, const float* __restrict__ gbias,
    const float* __restrict__ a_ptr, float* __restrict__ out_f,
    short* __restrict__ out_b, int N)
{
    const float a = a_ptr[0];
    int gid = blockIdx.x * blockDim.x + threadIdx.x;
    int r = gid >> 6;
    int l = gid & 63;
    if (r >= N) return;

    int beg = offsets[r], end = offsets[r + 1];
    float2 acc0 = make_float2(0.f, 0.f), acc1 = acc0, acc2 = acc0, acc3 = acc0;
    int e = beg;
    for (; e + 4 <= end; e += 4) {
        EdgeCW e0 = cw[e],     e1 = cw[e + 1];
        EdgeCW e2 = cw[e + 2], e3 = cw[e + 3];
        unsigned u0 = *reinterpret_cast<const unsigned*>(s_bf + (size_t)e0.c * H + 2 * l);
        unsigned u1 = *reinterpret_cast<const unsigned*>(s_bf + (size_t)e1.c * H + 2 * l);
        unsigned u2 = *reinterpret_cast<const unsigned*>(s_bf + (size_t)e2.c * H + 2 * l);
        unsigned u3 = *reinterpret_cast<const unsigned*>(s_bf + (size_t)e3.c * H + 2 * l);
        acc0.x += e0.w * bflo(u0); acc0.y += e0.w * bfhi(u0);
        acc1.x += e1.w * bflo(u1); acc1.y += e1.w * bfhi(u1);
        acc2.x += e2.w * bflo(u2); acc2.y += e2.w * bfhi(u2);
        acc3.x += e3.w * bflo(u3); acc3.y += e3.w * bfhi(u3);
    }
    for (; e < end; ++e) {
        EdgeCW e0 = cw[e];
        unsigned u0 = *reinterpret_cast<const unsigned*>(s_bf + (size_t)e0.c * H + 2 * l);
        acc0.x += e0.w * bflo(u0); acc0.y += e0.w * bfhi(u0);
    }

    float2 g = *reinterpret_cast<const float2*>(gbias + l * 2);
    float vx = (acc0.x + acc1.x) + (acc2.x + acc3.x) + g.x;
    float vy = (acc0.y + acc1.y) + (acc2.y + acc3.y) + g.y;
    vx = vx > 0.f ? vx : a * vx;
    vy = vy > 0.f ? vy : a * vy;

    if (MODE == 0)
        *reinterpret_cast<float2*>(out_f + (size_t)r * H + l * 2) = make_float2(vx, vy);
    else {
        unsigned pack = (unsigned)f2bf(vx) | ((unsigned)f2bf(vy) << 16);
        *reinterpret_cast<unsigned*>(out_b + (size_t)r * H + l * 2) = pack;
    }
}

// ===========================================================================
// Fallback path (ws too small for CSR): atomic scatter SpMM over bf16 s
// ===========================================================================
__global__ __launch_bounds__(256) void init_out_kernel(
    float* __restrict__ out, const float* __restrict__ gbias, int total4)
{
    int i = blockIdx.x * blockDim.x + threadIdx.x;
    const int stride = gridDim.x * blockDim.x;
    for (; i < total4; i += stride) {
        int c4 = i & 31;
        float4 bv = *reinterpret_cast<const float4*>(gbias + c4 * 4);
        *reinterpret_cast<float4*>(out + (size_t)i * 4) = bv;
    }
}

__global__ __launch_bounds__(256) void spmm_edge_kernel(
    const int* __restrict__ erow, const int* __restrict__ ecol,
    const float* __restrict__ ew, const short* __restrict__ s_bf,
    float* __restrict__ out, int E)
{
    long long gid = (long long)blockIdx.x * blockDim.x + threadIdx.x;
    int e = (int)(gid >> 6);
    int l = (int)(gid & 63);
    if (e >= E) return;
    int r = erow[e];
    int c = ecol[e];
    float w = ew[e];
    unsigned u = *reinterpret_cast<const unsigned*>(s_bf + (size_t)c * H + 2 * l);
    unsafeAtomicAdd(out + (size_t)r * H + l * 2 + 0, bflo(u) * w);
    unsafeAtomicAdd(out + (size_t)r * H + l * 2 + 1, bfhi(u) * w);
}

__global__ __launch_bounds__(256) void prelu_kernel(
    float* __restrict__ buf, const float* __restrict__ a_ptr, int total4)
{
    const float a = a_ptr[0];
    int i = blockIdx.x * blockDim.x + threadIdx.x;
    const int stride = gridDim.x * blockDim.x;
    for (; i < total4; i += stride) {
        float4 v = *reinterpret_cast<float4*>(buf + (size_t)i * 4);
        v.x = v.x > 0.f ? v.x : a * v.x;
        v.y = v.y > 0.f ? v.y : a * v.y;
        v.z = v.z > 0.f ? v.z : a * v.z;
        v.w = v.w > 0.f ? v.w : a * v.w;
        *reinterpret_cast<float4*>(buf + (size_t)i * 4) = v;
    }
}

// ===========================================================================
extern "C" void kernel_launch(void* const* d_in, const int* in_sizes, int n_in,
                              void* d_out, int out_size, void* d_ws, size_t ws_size,
                              hipStream_t stream)
{
    const float* h        = (const float*)d_in[0];
    const int*   erow     = (const int*)d_in[1];
    const int*   ecol     = (const int*)d_in[2];
    const float* ew       = (const float*)d_in[3];
    const float* fc_w     = (const float*)d_in[4];  // [2][H][H]
    const float* fc_b     = (const float*)d_in[5];  // [2][H]
    const float* gcn_bias = (const float*)d_in[6];  // [2][H]
    const float* prelu_a  = (const float*)d_in[7];  // [2]

    const int N = in_sizes[0] / H;
    const int E = in_sizes[1];
    float* out = (float*)d_out;

    // ---- workspace layout ----
    char* ws = (char*)d_ws;
    short* s_bf  = (short*)ws;                       // N*H bf16 (GEMM out / spmm in)
    size_t off = (size_t)N * H * sizeof(short);
    short* x1_bf = (short*)(ws + off); off += (size_t)N * H * sizeof(short);
    int* counts  = (int*)(ws + off); off += (size_t)N * 4;
    int* incl    = (int*)(ws + off); off += (size_t)N * 4;
    int* offsets = (int*)(ws + off); off += (size_t)(N + 1) * 4;
    int* cursor  = (int*)(ws + off); off += (size_t)N * 4;
    const int nb_scan = (N + SCAN_BLK - 1) / SCAN_BLK;
    int* bsums   = (int*)(ws + off); off += (size_t)nb_scan * 4;
    off = (off + 7) & ~(size_t)7;
    EdgeCW* cw   = (EdgeCW*)(ws + off); off += (size_t)E * sizeof(EdgeCW);

    const int eblocks = (E + 255) / 256;
    const int nbatch = (N + MB - 1) / MB;
    const int ggrid = nbatch < 1024 ? nbatch : 1024;

    if (off <= ws_size) {
        // ---- CSR build ----
        zero_kernel<<<(N + 255) / 256, 256, 0, stream>>>(counts, N);
        count_kernel<<<eblocks, 256, 0, stream>>>(erow, counts, E);
        scan_block_kernel<<<nb_scan, SCAN_BLK, 0, stream>>>(counts, incl, bsums, N);
        scan_sums_kernel<<<1, SCAN_BLK, 0, stream>>>(bsums, nb_scan);
        finalize_offsets_kernel<<<nb_scan, SCAN_BLK, 0, stream>>>(
            counts, incl, bsums, offsets, cursor, N, E);
        fill_kernel<<<eblocks, 256, 0, stream>>>(erow, ecol, ew, cursor, cw, E);

        const int spmm_blocks = (int)(((long long)N * 64 + 255) / 256);

        // ---- layer 0 ----
        gemm_mfma_kernel<false><<<ggrid, 256, 0, stream>>>(h, fc_w, fc_b, s_bf, N, nbatch);
        spmm_csr_kernel<1><<<spmm_blocks, 256, 0, stream>>>(
            offsets, cw, s_bf, gcn_bias, prelu_a, nullptr, x1_bf, N);
        // ---- layer 1 ----
        gemm_mfma_kernel<true><<<ggrid, 256, 0, stream>>>(x1_bf, fc_w + H * H, fc_b + H, s_bf, N, nbatch);
        spmm_csr_kernel<0><<<spmm_blocks, 256, 0, stream>>>(
            offsets, cw, s_bf, gcn_bias + H, prelu_a + 1, out, nullptr, N);
    } else {
        // ---- fallback: atomic scatter path (needs only s_bf = N*H*2 bytes) ----
        const int total4 = N * (H / 4);
        const int spmm_blocks = (int)(((long long)E * 64 + 255) / 256);

        gemm_mfma_kernel<false><<<ggrid, 256, 0, stream>>>(h, fc_w, fc_b, s_bf, N, nbatch);
        init_out_kernel<<<2048, 256, 0, stream>>>(out, gcn_bias, total4);
        spmm_edge_kernel<<<spmm_blocks, 256, 0, stream>>>(erow, ecol, ew, s_bf, out, E);
        prelu_kernel<<<2048, 256, 0, stream>>>(out, prelu_a, total4);

        gemm_mfma_kernel<false><<<ggrid, 256, 0, stream>>>(out, fc_w + H * H, fc_b + H, s_bf, N, nbatch);
        init_out_kernel<<<2048, 256, 0, stream>>>(out, gcn_bias + H, total4);
        spmm_edge_kernel<<<spmm_blocks, 256, 0, stream>>>(erow, ecol, ew, s_bf, out, E);
        prelu_kernel<<<2048, 256, 0, stream>>>(out, prelu_a + 1, total4);
    }
}

// Round 6
// 183.558 us; speedup vs baseline: 6.4250x; 1.1150x over previous
//
#include <hip/hip_runtime.h>

#define H 128

typedef __attribute__((ext_vector_type(8))) short bf16x8;
typedef __attribute__((ext_vector_type(4))) short s16x4;
typedef __attribute__((ext_vector_type(4))) float f32x4;

__device__ inline unsigned short f2bf(float f) {
    unsigned u = __float_as_uint(f);
    unsigned r = (u + 0x7fffu + ((u >> 16) & 1u)) >> 16;  // RNE
    return (unsigned short)r;
}
__device__ inline float bflo(unsigned u) { return __uint_as_float(u << 16); }
__device__ inline float bfhi(unsigned u) { return __uint_as_float(u & 0xffff0000u); }

struct EdgeCW { int c; float w; };   // 8 bytes

// ===========================================================================
// GEMM body (shared by standalone + merged kernels):
// s_bf[n][j] = bf16( sum_k x[n][k]*W[j][k] + b[j] )
// 256 thr = 4 waves. W staged bf16 in LDS (34 KB, padded rows) once; x frags
// direct global->VGPR; operand-swapped MFMA (D lanes = n, regs = j) so the
// epilogue stores 8 B of 4 consecutive bf16 cols.
// ===========================================================================
#define MB 64

template<bool BF16IN>
__device__ __forceinline__ void gemm_body(
    short* wlds, const void* __restrict__ xv, const float* __restrict__ W,
    const float* __restrict__ b, short* __restrict__ s_out, int N, int nbatch,
    int bid, int grid)
{
    const int t = threadIdx.x;
    const int l = t & 63;
    const int w = t >> 6;
    const int n_g   = (w & 1) * 32;
    const int col_g = (w >> 1) * 64;
    const int ln15 = l & 15;
    const int lhi  = l >> 4;

    #pragma unroll
    for (int i = 0; i < 16; ++i) {
        int fidx = i * 256 + t;          // 4096 float4 chunks
        int j  = fidx >> 5;
        int c4 = fidx & 31;
        float4 v = *reinterpret_cast<const float4*>(W + (size_t)j * H + c4 * 4);
        s16x4 p;
        p[0] = (short)f2bf(v.x); p[1] = (short)f2bf(v.y);
        p[2] = (short)f2bf(v.z); p[3] = (short)f2bf(v.w);
        *reinterpret_cast<s16x4*>(&wlds[j * 136 + c4 * 4]) = p;
    }

    float4 bias4[4];
    #pragma unroll
    for (int jt = 0; jt < 4; ++jt)
        bias4[jt] = *reinterpret_cast<const float4*>(b + col_g + jt * 16 + lhi * 4);

    __syncthreads();   // wlds ready; read-only hereafter

    for (int batch = bid; batch < nbatch; batch += grid) {
        const int row0 = batch * MB;

        bf16x8 ax[4][2];
        #pragma unroll
        for (int nf = 0; nf < 2; ++nf) {
            const int n = row0 + n_g + nf * 16 + ln15;
            const bool ok = (n < N);
            #pragma unroll
            for (int ks = 0; ks < 4; ++ks) {
                bf16x8 f = {0, 0, 0, 0, 0, 0, 0, 0};
                if (ok) {
                    if (BF16IN) {
                        f = *reinterpret_cast<const bf16x8*>(
                            (const short*)xv + (size_t)n * H + ks * 32 + lhi * 8);
                    } else {
                        const float* p = (const float*)xv + (size_t)n * H + ks * 32 + lhi * 8;
                        float4 lo = *reinterpret_cast<const float4*>(p);
                        float4 hi = *reinterpret_cast<const float4*>(p + 4);
                        f[0] = (short)f2bf(lo.x); f[1] = (short)f2bf(lo.y);
                        f[2] = (short)f2bf(lo.z); f[3] = (short)f2bf(lo.w);
                        f[4] = (short)f2bf(hi.x); f[5] = (short)f2bf(hi.y);
                        f[6] = (short)f2bf(hi.z); f[7] = (short)f2bf(hi.w);
                    }
                }
                ax[ks][nf] = f;
            }
        }

        f32x4 acc[2][4] = {};
        #pragma unroll
        for (int ks = 0; ks < 4; ++ks) {
            #pragma unroll
            for (int jt = 0; jt < 4; ++jt) {
                bf16x8 aw = *reinterpret_cast<const bf16x8*>(
                    &wlds[(col_g + jt * 16 + ln15) * 136 + ks * 32 + lhi * 8]);
                acc[0][jt] = __builtin_amdgcn_mfma_f32_16x16x32_bf16(
                    aw, ax[ks][0], acc[0][jt], 0, 0, 0);
                acc[1][jt] = __builtin_amdgcn_mfma_f32_16x16x32_bf16(
                    aw, ax[ks][1], acc[1][jt], 0, 0, 0);
            }
        }

        #pragma unroll
        for (int nf = 0; nf < 2; ++nf) {
            const int n = row0 + n_g + nf * 16 + ln15;
            if (n < N) {
                #pragma unroll
                for (int jt = 0; jt < 4; ++jt) {
                    s16x4 p;
                    p[0] = (short)f2bf(acc[nf][jt][0] + bias4[jt].x);
                    p[1] = (short)f2bf(acc[nf][jt][1] + bias4[jt].y);
                    p[2] = (short)f2bf(acc[nf][jt][2] + bias4[jt].z);
                    p[3] = (short)f2bf(acc[nf][jt][3] + bias4[jt].w);
                    *reinterpret_cast<s16x4*>(
                        s_out + (size_t)n * H + col_g + jt * 16 + lhi * 4) = p;
                }
            }
        }
    }
}

template<bool BF16IN>
__global__ __launch_bounds__(256) void gemm_mfma_kernel(
    const void* __restrict__ xv, const float* __restrict__ W,
    const float* __restrict__ b, short* __restrict__ s_out, int N, int nbatch)
{
    __shared__ short wlds[H * 136];
    gemm_body<BF16IN>(wlds, xv, W, b, s_out, N, nbatch, blockIdx.x, gridDim.x);
}

// Merged dispatch: blocks [0, fill_blocks) do CSR fill; the rest run gemm0.
// fill and gemm0 are mutually independent; co-dispatch overlaps them on the
// single stream (fill ~scatter-bound, gemm ~MFMA/stream-bound).
__global__ __launch_bounds__(256) void fill_plus_gemm_kernel(
    const int* __restrict__ erow, const int* __restrict__ ecol,
    const float* __restrict__ ew, int* __restrict__ cursor,
    EdgeCW* __restrict__ cw, int E, int fill_blocks,
    const void* __restrict__ xv, const float* __restrict__ W,
    const float* __restrict__ b, short* __restrict__ s_out, int N, int nbatch,
    int gemm_grid)
{
    __shared__ short wlds[H * 136];
    if ((int)blockIdx.x < fill_blocks) {
        int e = blockIdx.x * 256 + threadIdx.x;
        if (e < E) {
            int r = erow[e];
            int pos = atomicAdd(&cursor[r], 1);
            EdgeCW x; x.c = ecol[e]; x.w = ew[e];
            cw[pos] = x;
        }
        return;
    }
    gemm_body<false>(wlds, xv, W, b, s_out, N, nbatch,
                     (int)blockIdx.x - fill_blocks, gemm_grid);
}

// ===========================================================================
// CSR build helpers
// ===========================================================================
__global__ __launch_bounds__(256) void count_kernel(
    const int* __restrict__ erow, int* __restrict__ counts, int E)
{
    int e = blockIdx.x * blockDim.x + threadIdx.x;
    if (e < E) atomicAdd(&counts[erow[e]], 1);
}

#define SCAN_BLK 1024
__global__ __launch_bounds__(SCAN_BLK) void scan_block_kernel(
    const int* __restrict__ counts, int* __restrict__ incl,
    int* __restrict__ bsums, int N)
{
    __shared__ int sm[SCAN_BLK];
    int i = blockIdx.x * SCAN_BLK + threadIdx.x;
    int v = (i < N) ? counts[i] : 0;
    sm[threadIdx.x] = v;
    __syncthreads();
    for (int off = 1; off < SCAN_BLK; off <<= 1) {
        int tv = (threadIdx.x >= off) ? sm[threadIdx.x - off] : 0;
        __syncthreads();
        sm[threadIdx.x] += tv;
        __syncthreads();
    }
    if (i < N) incl[i] = sm[threadIdx.x];
    if (threadIdx.x == SCAN_BLK - 1) bsums[blockIdx.x] = sm[SCAN_BLK - 1];
}

__global__ __launch_bounds__(SCAN_BLK) void scan_sums_kernel(int* __restrict__ bsums, int nb)
{
    __shared__ int sm[SCAN_BLK];
    if (nb <= SCAN_BLK) {
        int i = threadIdx.x;
        int v = (i < nb) ? bsums[i] : 0;
        sm[i] = v;
        __syncthreads();
        for (int off = 1; off < SCAN_BLK; off <<= 1) {
            int tv = (i >= off) ? sm[i - off] : 0;
            __syncthreads();
            sm[i] += tv;
            __syncthreads();
        }
        if (i < nb) bsums[i] = sm[i] - v;   // exclusive
    } else if (threadIdx.x == 0) {
        int run = 0;
        for (int i = 0; i < nb; ++i) { int v = bsums[i]; bsums[i] = run; run += v; }
    }
}

__global__ __launch_bounds__(SCAN_BLK) void finalize_offsets_kernel(
    const int* __restrict__ counts, const int* __restrict__ incl,
    const int* __restrict__ bsums, int* __restrict__ offsets,
    int* __restrict__ cursor, int N, int E)
{
    int i = blockIdx.x * SCAN_BLK + threadIdx.x;
    if (i < N) {
        int start = incl[i] - counts[i] + bsums[blockIdx.x];
        offsets[i] = start;
        cursor[i]  = start;
    }
    if (i == 0) offsets[N] = E;
}

// ===========================================================================
// SpMM v2 (CSR, gather-only, bf16 s) fused with gcn_bias + PReLU.
// One wave = 2 rows; half-wave (32 lanes) per row, lane li owns cols
// [4li, 4li+3] (u64 load = 4 bf16). 4-deep unrolled accumulator chains.
// MODE: 0 = write f32 out (float4), 1 = write bf16 out (8 B pack).
// ===========================================================================
template<int MODE>
__global__ __launch_bounds__(256) void spmm_csr2_kernel(
    const int* __restrict__ offsets, const EdgeCW* __restrict__ cw,
    const short* __restrict__ s_bf, const float* __restrict__ gbias,
    const float* __restrict__ a_ptr, float* __restrict__ out_f,
    short* __restrict__ out_b, int N)
{
    const float a = a_ptr[0];
    int gid = blockIdx.x * blockDim.x + threadIdx.x;
    int wid  = gid >> 6;
    int l    = gid & 63;
    int half = l >> 5;
    int li   = l & 31;
    int r = wid * 2 + half;
    if (r >= N) return;

    const int beg = offsets[r], end = offsets[r + 1];
    const size_t coff = (size_t)li * 4;

    float a00=0.f,a01=0.f,a02=0.f,a03=0.f;
    float a10=0.f,a11=0.f,a12=0.f,a13=0.f;
    float a20=0.f,a21=0.f,a22=0.f,a23=0.f;
    float a30=0.f,a31=0.f,a32=0.f,a33=0.f;

    int e = beg;
    for (; e + 4 <= end; e += 4) {
        EdgeCW e0 = cw[e],     e1 = cw[e + 1];
        EdgeCW e2 = cw[e + 2], e3 = cw[e + 3];
        unsigned long long u0 = *reinterpret_cast<const unsigned long long*>(
            s_bf + (size_t)e0.c * H + coff);
        unsigned long long u1 = *reinterpret_cast<const unsigned long long*>(
            s_bf + (size_t)e1.c * H + coff);
        unsigned long long u2 = *reinterpret_cast<const unsigned long long*>(
            s_bf + (size_t)e2.c * H + coff);
        unsigned long long u3 = *reinterpret_cast<const unsigned long long*>(
            s_bf + (size_t)e3.c * H + coff);
        unsigned lo;
        lo = (unsigned)u0; a00 += e0.w * bflo(lo); a01 += e0.w * bfhi(lo);
        lo = (unsigned)(u0 >> 32); a02 += e0.w * bflo(lo); a03 += e0.w * bfhi(lo);
        lo = (unsigned)u1; a10 += e1.w * bflo(lo); a11 += e1.w * bfhi(lo);
        lo = (unsigned)(u1 >> 32); a12 += e1.w * bflo(lo); a13 += e1.w * bfhi(lo);
        lo = (unsigned)u2; a20 += e2.w * bflo(lo); a21 += e2.w * bfhi(lo);
        lo = (unsigned)(u2 >> 32); a22 += e2.w * bflo(lo); a23 += e2.w * bfhi(lo);
        lo = (unsigned)u3; a30 += e3.w * bflo(lo); a31 += e3.w * bfhi(lo);
        lo = (unsigned)(u3 >> 32); a32 += e3.w * bflo(lo); a33 += e3.w * bfhi(lo);
    }
    for (; e < end; ++e) {
        EdgeCW e0 = cw[e];
        unsigned long long u0 = *reinterpret_cast<const unsigned long long*>(
            s_bf + (size_t)e0.c * H + coff);
        unsigned lo;
        lo = (unsigned)u0; a00 += e0.w * bflo(lo); a01 += e0.w * bfhi(lo);
        lo = (unsigned)(u0 >> 32); a02 += e0.w * bflo(lo); a03 += e0.w * bfhi(lo);
    }

    float4 g = *reinterpret_cast<const float4*>(gbias + li * 4);
    float v0 = (a00 + a10) + (a20 + a30) + g.x;
    float v1 = (a01 + a11) + (a21 + a31) + g.y;
    float v2 = (a02 + a12) + (a22 + a32) + g.z;
    float v3 = (a03 + a13) + (a23 + a33) + g.w;
    v0 = v0 > 0.f ? v0 : a * v0;
    v1 = v1 > 0.f ? v1 : a * v1;
    v2 = v2 > 0.f ? v2 : a * v2;
    v3 = v3 > 0.f ? v3 : a * v3;

    if (MODE == 0) {
        *reinterpret_cast<float4*>(out_f + (size_t)r * H + li * 4) =
            make_float4(v0, v1, v2, v3);
    } else {
        s16x4 p;
        p[0] = (short)f2bf(v0); p[1] = (short)f2bf(v1);
        p[2] = (short)f2bf(v2); p[3] = (short)f2bf(v3);
        *reinterpret_cast<s16x4*>(out_b + (size_t)r * H + li * 4) = p;
    }
}

// ===========================================================================
// Fallback path (ws too small for CSR): atomic scatter SpMM over bf16 s
// ===========================================================================
__global__ __launch_bounds__(256) void init_out_kernel(
    float* __restrict__ out, const float* __restrict__ gbias, int total4)
{
    int i = blockIdx.x * blockDim.x + threadIdx.x;
    const int stride = gridDim.x * blockDim.x;
    for (; i < total4; i += stride) {
        int c4 = i & 31;
        float4 bv = *reinterpret_cast<const float4*>(gbias + c4 * 4);
        *reinterpret_cast<float4*>(out + (size_t)i * 4) = bv;
    }
}

__global__ __launch_bounds__(256) void spmm_edge_kernel(
    const int* __restrict__ erow, const int* __restrict__ ecol,
    const float* __restrict__ ew, const short* __restrict__ s_bf,
    float* __restrict__ out, int E)
{
    long long gid = (long long)blockIdx.x * blockDim.x + threadIdx.x;
    int e = (int)(gid >> 6);
    int l = (int)(gid & 63);
    if (e >= E) return;
    int r = erow[e];
    int c = ecol[e];
    float w = ew[e];
    unsigned u = *reinterpret_cast<const unsigned*>(s_bf + (size_t)c * H + 2 * l);
    unsafeAtomicAdd(out + (size_t)r * H + l * 2 + 0, bflo(u) * w);
    unsafeAtomicAdd(out + (size_t)r * H + l * 2 + 1, bfhi(u) * w);
}

__global__ __launch_bounds__(256) void prelu_kernel(
    float* __restrict__ buf, const float* __restrict__ a_ptr, int total4)
{
    const float a = a_ptr[0];
    int i = blockIdx.x * blockDim.x + threadIdx.x;
    const int stride = gridDim.x * blockDim.x;
    for (; i < total4; i += stride) {
        float4 v = *reinterpret_cast<float4*>(buf + (size_t)i * 4);
        v.x = v.x > 0.f ? v.x : a * v.x;
        v.y = v.y > 0.f ? v.y : a * v.y;
        v.z = v.z > 0.f ? v.z : a * v.z;
        v.w = v.w > 0.f ? v.w : a * v.w;
        *reinterpret_cast<float4*>(buf + (size_t)i * 4) = v;
    }
}

// ===========================================================================
extern "C" void kernel_launch(void* const* d_in, const int* in_sizes, int n_in,
                              void* d_out, int out_size, void* d_ws, size_t ws_size,
                              hipStream_t stream)
{
    const float* h        = (const float*)d_in[0];
    const int*   erow     = (const int*)d_in[1];
    const int*   ecol     = (const int*)d_in[2];
    const float* ew       = (const float*)d_in[3];
    const float* fc_w     = (const float*)d_in[4];  // [2][H][H]
    const float* fc_b     = (const float*)d_in[5];  // [2][H]
    const float* gcn_bias = (const float*)d_in[6];  // [2][H]
    const float* prelu_a  = (const float*)d_in[7];  // [2]

    const int N = in_sizes[0] / H;
    const int E = in_sizes[1];
    float* out = (float*)d_out;

    // ---- workspace layout ----
    char* ws = (char*)d_ws;
    short* s_bf  = (short*)ws;                       // N*H bf16 (GEMM out / spmm in)
    size_t off = (size_t)N * H * sizeof(short);
    short* x1_bf = (short*)(ws + off); off += (size_t)N * H * sizeof(short);
    int* counts  = (int*)(ws + off); off += (size_t)N * 4;
    int* incl    = (int*)(ws + off); off += (size_t)N * 4;
    int* offsets = (int*)(ws + off); off += (size_t)(N + 1) * 4;
    int* cursor  = (int*)(ws + off); off += (size_t)N * 4;
    const int nb_scan = (N + SCAN_BLK - 1) / SCAN_BLK;
    int* bsums   = (int*)(ws + off); off += (size_t)nb_scan * 4;
    off = (off + 7) & ~(size_t)7;
    EdgeCW* cw   = (EdgeCW*)(ws + off); off += (size_t)E * sizeof(EdgeCW);

    const int eblocks = (E + 255) / 256;
    const int nbatch = (N + MB - 1) / MB;
    const int ggrid = nbatch < 1024 ? nbatch : 1024;

    if (off <= ws_size) {
        // ---- CSR build, gemm0 overlapped with fill ----
        hipMemsetAsync(counts, 0, (size_t)N * 4, stream);
        count_kernel<<<eblocks, 256, 0, stream>>>(erow, counts, E);
        scan_block_kernel<<<nb_scan, SCAN_BLK, 0, stream>>>(counts, incl, bsums, N);
        scan_sums_kernel<<<1, SCAN_BLK, 0, stream>>>(bsums, nb_scan);
        finalize_offsets_kernel<<<nb_scan, SCAN_BLK, 0, stream>>>(
            counts, incl, bsums, offsets, cursor, N, E);
        fill_plus_gemm_kernel<<<eblocks + ggrid, 256, 0, stream>>>(
            erow, ecol, ew, cursor, cw, E, eblocks,
            h, fc_w, fc_b, s_bf, N, nbatch, ggrid);

        const int spmm_blocks = (int)((((long long)(N + 1) / 2) * 64 + 255) / 256);

        // ---- layer 0 tail + layer 1 ----
        spmm_csr2_kernel<1><<<spmm_blocks, 256, 0, stream>>>(
            offsets, cw, s_bf, gcn_bias, prelu_a, nullptr, x1_bf, N);
        gemm_mfma_kernel<true><<<ggrid, 256, 0, stream>>>(
            x1_bf, fc_w + H * H, fc_b + H, s_bf, N, nbatch);
        spmm_csr2_kernel<0><<<spmm_blocks, 256, 0, stream>>>(
            offsets, cw, s_bf, gcn_bias + H, prelu_a + 1, out, nullptr, N);
    } else {
        // ---- fallback: atomic scatter path (needs only s_bf = N*H*2 bytes) ----
        const int total4 = N * (H / 4);
        const int spmm_blocks = (int)(((long long)E * 64 + 255) / 256);

        gemm_mfma_kernel<false><<<ggrid, 256, 0, stream>>>(h, fc_w, fc_b, s_bf, N, nbatch);
        init_out_kernel<<<2048, 256, 0, stream>>>(out, gcn_bias, total4);
        spmm_edge_kernel<<<spmm_blocks, 256, 0, stream>>>(erow, ecol, ew, s_bf, out, E);
        prelu_kernel<<<2048, 256, 0, stream>>>(out, prelu_a, total4);

        gemm_mfma_kernel<false><<<ggrid, 256, 0, stream>>>(out, fc_w + H * H, fc_b + H, s_bf, N, nbatch);
        init_out_kernel<<<2048, 256, 0, stream>>>(out, gcn_bias + H, total4);
        spmm_edge_kernel<<<spmm_blocks, 256, 0, stream>>>(erow, ecol, ew, s_bf, out, E);
        prelu_kernel<<<2048, 256, 0, stream>>>(out, prelu_a + 1, total4);
    }
}

// Round 7
// 163.833 us; speedup vs baseline: 7.1985x; 1.1204x over previous
//
#include <hip/hip_runtime.h>

#define H 128

typedef __attribute__((ext_vector_type(8))) short bf16x8;
typedef __attribute__((ext_vector_type(4))) short s16x4;
typedef __attribute__((ext_vector_type(4))) float f32x4;

__device__ inline unsigned short f2bf(float f) {
    unsigned u = __float_as_uint(f);
    unsigned r = (u + 0x7fffu + ((u >> 16) & 1u)) >> 16;  // RNE
    return (unsigned short)r;
}
__device__ inline float bflo(unsigned u) { return __uint_as_float(u << 16); }
__device__ inline float bfhi(unsigned u) { return __uint_as_float(u & 0xffff0000u); }

// packed edge: col in high 17 bits, weight as 15-bit fixed point (w in [0,1))
__device__ inline unsigned pack_cw(int c, float w) {
    unsigned q = (unsigned)(w * 32768.f);
    if (q > 32767u) q = 32767u;
    return ((unsigned)c << 15) | q;
}

// ===========================================================================
// GEMM: s_bf[n][j] = bf16( sum_k x[n][k]*W[j][k] + b[j] )
// 256 thr = 4 waves. W staged bf16 in LDS (34 KB, padded rows) once; x frags
// direct global->VGPR; operand-swapped MFMA (D lanes = n, regs = j) so the
// epilogue stores 8 B of 4 consecutive bf16 cols. grid 1024 = 4 blocks/CU
// (LDS-limited full residency).
// ===========================================================================
#define MB 64

template<bool BF16IN>
__global__ __launch_bounds__(256) void gemm_mfma_kernel(
    const void* __restrict__ xv, const float* __restrict__ W,
    const float* __restrict__ b, short* __restrict__ s_out, int N, int nbatch)
{
    __shared__ short wlds[H * 136];

    const int t = threadIdx.x;
    const int l = t & 63;
    const int w = t >> 6;
    const int n_g   = (w & 1) * 32;
    const int col_g = (w >> 1) * 64;
    const int ln15 = l & 15;
    const int lhi  = l >> 4;

    #pragma unroll
    for (int i = 0; i < 16; ++i) {
        int fidx = i * 256 + t;          // 4096 float4 chunks
        int j  = fidx >> 5;
        int c4 = fidx & 31;
        float4 v = *reinterpret_cast<const float4*>(W + (size_t)j * H + c4 * 4);
        s16x4 p;
        p[0] = (short)f2bf(v.x); p[1] = (short)f2bf(v.y);
        p[2] = (short)f2bf(v.z); p[3] = (short)f2bf(v.w);
        *reinterpret_cast<s16x4*>(&wlds[j * 136 + c4 * 4]) = p;
    }

    float4 bias4[4];
    #pragma unroll
    for (int jt = 0; jt < 4; ++jt)
        bias4[jt] = *reinterpret_cast<const float4*>(b + col_g + jt * 16 + lhi * 4);

    __syncthreads();   // wlds ready; read-only hereafter

    for (int batch = blockIdx.x; batch < nbatch; batch += gridDim.x) {
        const int row0 = batch * MB;

        bf16x8 ax[4][2];
        #pragma unroll
        for (int nf = 0; nf < 2; ++nf) {
            const int n = row0 + n_g + nf * 16 + ln15;
            const bool ok = (n < N);
            #pragma unroll
            for (int ks = 0; ks < 4; ++ks) {
                bf16x8 f = {0, 0, 0, 0, 0, 0, 0, 0};
                if (ok) {
                    if (BF16IN) {
                        f = *reinterpret_cast<const bf16x8*>(
                            (const short*)xv + (size_t)n * H + ks * 32 + lhi * 8);
                    } else {
                        const float* p = (const float*)xv + (size_t)n * H + ks * 32 + lhi * 8;
                        float4 lo = *reinterpret_cast<const float4*>(p);
                        float4 hi = *reinterpret_cast<const float4*>(p + 4);
                        f[0] = (short)f2bf(lo.x); f[1] = (short)f2bf(lo.y);
                        f[2] = (short)f2bf(lo.z); f[3] = (short)f2bf(lo.w);
                        f[4] = (short)f2bf(hi.x); f[5] = (short)f2bf(hi.y);
                        f[6] = (short)f2bf(hi.z); f[7] = (short)f2bf(hi.w);
                    }
                }
                ax[ks][nf] = f;
            }
        }

        f32x4 acc[2][4] = {};
        #pragma unroll
        for (int ks = 0; ks < 4; ++ks) {
            #pragma unroll
            for (int jt = 0; jt < 4; ++jt) {
                bf16x8 aw = *reinterpret_cast<const bf16x8*>(
                    &wlds[(col_g + jt * 16 + ln15) * 136 + ks * 32 + lhi * 8]);
                acc[0][jt] = __builtin_amdgcn_mfma_f32_16x16x32_bf16(
                    aw, ax[ks][0], acc[0][jt], 0, 0, 0);
                acc[1][jt] = __builtin_amdgcn_mfma_f32_16x16x32_bf16(
                    aw, ax[ks][1], acc[1][jt], 0, 0, 0);
            }
        }

        #pragma unroll
        for (int nf = 0; nf < 2; ++nf) {
            const int n = row0 + n_g + nf * 16 + ln15;
            if (n < N) {
                #pragma unroll
                for (int jt = 0; jt < 4; ++jt) {
                    s16x4 p;
                    p[0] = (short)f2bf(acc[nf][jt][0] + bias4[jt].x);
                    p[1] = (short)f2bf(acc[nf][jt][1] + bias4[jt].y);
                    p[2] = (short)f2bf(acc[nf][jt][2] + bias4[jt].z);
                    p[3] = (short)f2bf(acc[nf][jt][3] + bias4[jt].w);
                    *reinterpret_cast<s16x4*>(
                        s_out + (size_t)n * H + col_g + jt * 16 + lhi * 4) = p;
                }
            }
        }
    }
}

// ===========================================================================
// CSR build: count (keeping atomic rank) -> scan -> atomic-free fill
// ===========================================================================
__global__ __launch_bounds__(256) void count_rank_kernel(
    const int* __restrict__ erow, int* __restrict__ counts,
    int* __restrict__ rank, int E)
{
    int e = blockIdx.x * blockDim.x + threadIdx.x;
    if (e < E) rank[e] = atomicAdd(&counts[erow[e]], 1);
}

#define SCAN_BLK 1024
__global__ __launch_bounds__(SCAN_BLK) void scan_block_kernel(
    const int* __restrict__ counts, int* __restrict__ incl,
    int* __restrict__ bsums, int N)
{
    __shared__ int sm[SCAN_BLK];
    int i = blockIdx.x * SCAN_BLK + threadIdx.x;
    int v = (i < N) ? counts[i] : 0;
    sm[threadIdx.x] = v;
    __syncthreads();
    for (int off = 1; off < SCAN_BLK; off <<= 1) {
        int tv = (threadIdx.x >= off) ? sm[threadIdx.x - off] : 0;
        __syncthreads();
        sm[threadIdx.x] += tv;
        __syncthreads();
    }
    if (i < N) incl[i] = sm[threadIdx.x];
    if (threadIdx.x == SCAN_BLK - 1) bsums[blockIdx.x] = sm[SCAN_BLK - 1];
}

__global__ __launch_bounds__(SCAN_BLK) void scan_sums_kernel(int* __restrict__ bsums, int nb)
{
    __shared__ int sm[SCAN_BLK];
    if (nb <= SCAN_BLK) {
        int i = threadIdx.x;
        int v = (i < nb) ? bsums[i] : 0;
        sm[i] = v;
        __syncthreads();
        for (int off = 1; off < SCAN_BLK; off <<= 1) {
            int tv = (i >= off) ? sm[i - off] : 0;
            __syncthreads();
            sm[i] += tv;
            __syncthreads();
        }
        if (i < nb) bsums[i] = sm[i] - v;   // exclusive
    } else if (threadIdx.x == 0) {
        int run = 0;
        for (int i = 0; i < nb; ++i) { int v = bsums[i]; bsums[i] = run; run += v; }
    }
}

__global__ __launch_bounds__(SCAN_BLK) void finalize_offsets_kernel(
    const int* __restrict__ counts, const int* __restrict__ incl,
    const int* __restrict__ bsums, int* __restrict__ offsets, int N, int E)
{
    int i = blockIdx.x * SCAN_BLK + threadIdx.x;
    if (i < N) offsets[i] = incl[i] - counts[i] + bsums[blockIdx.x];
    if (i == 0) offsets[N] = E;
}

// atomic-free fill: pos = offsets[row] + rank (rank captured during count)
__global__ __launch_bounds__(256) void fill_kernel(
    const int* __restrict__ erow, const int* __restrict__ ecol,
    const float* __restrict__ ew, const int* __restrict__ offsets,
    const int* __restrict__ rank, unsigned* __restrict__ cw, int E)
{
    int e = blockIdx.x * blockDim.x + threadIdx.x;
    if (e < E) {
        int r = erow[e];
        cw[offsets[r] + rank[e]] = pack_cw(ecol[e], ew[e]);
    }
}

// ===========================================================================
// SpMM v2 (CSR, gather-only, bf16 s, packed 4B edges) + gcn_bias + PReLU.
// One wave = 2 rows; half-wave (32 lanes) per row, lane li owns cols
// [4li, 4li+3] (u64 load = 4 bf16). 4-deep unrolled accumulator chains.
// MODE: 0 = write f32 out (float4), 1 = write bf16 out (8 B pack).
// ===========================================================================
template<int MODE>
__global__ __launch_bounds__(256) void spmm_csr2_kernel(
    const int* __restrict__ offsets, const unsigned* __restrict__ cw,
    const short* __restrict__ s_bf, const float* __restrict__ gbias,
    const float* __restrict__ a_ptr, float* __restrict__ out_f,
    short* __restrict__ out_b, int N)
{
    const float a = a_ptr[0];
    int gid = blockIdx.x * blockDim.x + threadIdx.x;
    int wid  = gid >> 6;
    int l    = gid & 63;
    int half = l >> 5;
    int li   = l & 31;
    int r = wid * 2 + half;
    if (r >= N) return;

    const int beg = offsets[r], end = offsets[r + 1];
    const size_t coff = (size_t)li * 4;
    const float SC = 1.f / 32768.f;

    float a00=0.f,a01=0.f,a02=0.f,a03=0.f;
    float a10=0.f,a11=0.f,a12=0.f,a13=0.f;
    float a20=0.f,a21=0.f,a22=0.f,a23=0.f;
    float a30=0.f,a31=0.f,a32=0.f,a33=0.f;

    int e = beg;
    for (; e + 4 <= end; e += 4) {
        unsigned p0 = cw[e],     p1 = cw[e + 1];
        unsigned p2 = cw[e + 2], p3 = cw[e + 3];
        float w0 = (float)(p0 & 0x7fffu) * SC;
        float w1 = (float)(p1 & 0x7fffu) * SC;
        float w2 = (float)(p2 & 0x7fffu) * SC;
        float w3 = (float)(p3 & 0x7fffu) * SC;
        unsigned long long u0 = *reinterpret_cast<const unsigned long long*>(
            s_bf + (size_t)(p0 >> 15) * H + coff);
        unsigned long long u1 = *reinterpret_cast<const unsigned long long*>(
            s_bf + (size_t)(p1 >> 15) * H + coff);
        unsigned long long u2 = *reinterpret_cast<const unsigned long long*>(
            s_bf + (size_t)(p2 >> 15) * H + coff);
        unsigned long long u3 = *reinterpret_cast<const unsigned long long*>(
            s_bf + (size_t)(p3 >> 15) * H + coff);
        unsigned lo;
        lo = (unsigned)u0; a00 += w0 * bflo(lo); a01 += w0 * bfhi(lo);
        lo = (unsigned)(u0 >> 32); a02 += w0 * bflo(lo); a03 += w0 * bfhi(lo);
        lo = (unsigned)u1; a10 += w1 * bflo(lo); a11 += w1 * bfhi(lo);
        lo = (unsigned)(u1 >> 32); a12 += w1 * bflo(lo); a13 += w1 * bfhi(lo);
        lo = (unsigned)u2; a20 += w2 * bflo(lo); a21 += w2 * bfhi(lo);
        lo = (unsigned)(u2 >> 32); a22 += w2 * bflo(lo); a23 += w2 * bfhi(lo);
        lo = (unsigned)u3; a30 += w3 * bflo(lo); a31 += w3 * bfhi(lo);
        lo = (unsigned)(u3 >> 32); a32 += w3 * bflo(lo); a33 += w3 * bfhi(lo);
    }
    for (; e < end; ++e) {
        unsigned p0 = cw[e];
        float w0 = (float)(p0 & 0x7fffu) * SC;
        unsigned long long u0 = *reinterpret_cast<const unsigned long long*>(
            s_bf + (size_t)(p0 >> 15) * H + coff);
        unsigned lo;
        lo = (unsigned)u0; a00 += w0 * bflo(lo); a01 += w0 * bfhi(lo);
        lo = (unsigned)(u0 >> 32); a02 += w0 * bflo(lo); a03 += w0 * bfhi(lo);
    }

    float4 g = *reinterpret_cast<const float4*>(gbias + li * 4);
    float v0 = (a00 + a10) + (a20 + a30) + g.x;
    float v1 = (a01 + a11) + (a21 + a31) + g.y;
    float v2 = (a02 + a12) + (a22 + a32) + g.z;
    float v3 = (a03 + a13) + (a23 + a33) + g.w;
    v0 = v0 > 0.f ? v0 : a * v0;
    v1 = v1 > 0.f ? v1 : a * v1;
    v2 = v2 > 0.f ? v2 : a * v2;
    v3 = v3 > 0.f ? v3 : a * v3;

    if (MODE == 0) {
        *reinterpret_cast<float4*>(out_f + (size_t)r * H + li * 4) =
            make_float4(v0, v1, v2, v3);
    } else {
        s16x4 p;
        p[0] = (short)f2bf(v0); p[1] = (short)f2bf(v1);
        p[2] = (short)f2bf(v2); p[3] = (short)f2bf(v3);
        *reinterpret_cast<s16x4*>(out_b + (size_t)r * H + li * 4) = p;
    }
}

// ===========================================================================
// Fallback path (ws too small for CSR): atomic scatter SpMM over bf16 s
// ===========================================================================
__global__ __launch_bounds__(256) void init_out_kernel(
    float* __restrict__ out, const float* __restrict__ gbias, int total4)
{
    int i = blockIdx.x * blockDim.x + threadIdx.x;
    const int stride = gridDim.x * blockDim.x;
    for (; i < total4; i += stride) {
        int c4 = i & 31;
        float4 bv = *reinterpret_cast<const float4*>(gbias + c4 * 4);
        *reinterpret_cast<float4*>(out + (size_t)i * 4) = bv;
    }
}

__global__ __launch_bounds__(256) void spmm_edge_kernel(
    const int* __restrict__ erow, const int* __restrict__ ecol,
    const float* __restrict__ ew, const short* __restrict__ s_bf,
    float* __restrict__ out, int E)
{
    long long gid = (long long)blockIdx.x * blockDim.x + threadIdx.x;
    int e = (int)(gid >> 6);
    int l = (int)(gid & 63);
    if (e >= E) return;
    int r = erow[e];
    int c = ecol[e];
    float w = ew[e];
    unsigned u = *reinterpret_cast<const unsigned*>(s_bf + (size_t)c * H + 2 * l);
    unsafeAtomicAdd(out + (size_t)r * H + l * 2 + 0, bflo(u) * w);
    unsafeAtomicAdd(out + (size_t)r * H + l * 2 + 1, bfhi(u) * w);
}

__global__ __launch_bounds__(256) void prelu_kernel(
    float* __restrict__ buf, const float* __restrict__ a_ptr, int total4)
{
    const float a = a_ptr[0];
    int i = blockIdx.x * blockDim.x + threadIdx.x;
    const int stride = gridDim.x * blockDim.x;
    for (; i < total4; i += stride) {
        float4 v = *reinterpret_cast<float4*>(buf + (size_t)i * 4);
        v.x = v.x > 0.f ? v.x : a * v.x;
        v.y = v.y > 0.f ? v.y : a * v.y;
        v.z = v.z > 0.f ? v.z : a * v.z;
        v.w = v.w > 0.f ? v.w : a * v.w;
        *reinterpret_cast<float4*>(buf + (size_t)i * 4) = v;
    }
}

// ===========================================================================
extern "C" void kernel_launch(void* const* d_in, const int* in_sizes, int n_in,
                              void* d_out, int out_size, void* d_ws, size_t ws_size,
                              hipStream_t stream)
{
    const float* h        = (const float*)d_in[0];
    const int*   erow     = (const int*)d_in[1];
    const int*   ecol     = (const int*)d_in[2];
    const float* ew       = (const float*)d_in[3];
    const float* fc_w     = (const float*)d_in[4];  // [2][H][H]
    const float* fc_b     = (const float*)d_in[5];  // [2][H]
    const float* gcn_bias = (const float*)d_in[6];  // [2][H]
    const float* prelu_a  = (const float*)d_in[7];  // [2]

    const int N = in_sizes[0] / H;
    const int E = in_sizes[1];
    float* out = (float*)d_out;

    // ---- workspace layout ----
    char* ws = (char*)d_ws;
    short* s_bf  = (short*)ws;                       // N*H bf16 (GEMM out / spmm in)
    size_t off = (size_t)N * H * sizeof(short);
    short* x1_bf = (short*)(ws + off); off += (size_t)N * H * sizeof(short);
    int* counts  = (int*)(ws + off); off += (size_t)N * 4;
    int* incl    = (int*)(ws + off); off += (size_t)N * 4;
    int* offsets = (int*)(ws + off); off += (size_t)(N + 1) * 4;
    const int nb_scan = (N + SCAN_BLK - 1) / SCAN_BLK;
    int* bsums   = (int*)(ws + off); off += (size_t)nb_scan * 4;
    int* rank    = (int*)(ws + off); off += (size_t)E * 4;
    unsigned* cw = (unsigned*)(ws + off); off += (size_t)E * 4;

    const int eblocks = (E + 255) / 256;
    const int nbatch = (N + MB - 1) / MB;
    const int ggrid = nbatch < 1024 ? nbatch : 1024;

    if (off <= ws_size) {
        // ---- CSR build (atomic-free fill via rank captured in count) ----
        hipMemsetAsync(counts, 0, (size_t)N * 4, stream);
        count_rank_kernel<<<eblocks, 256, 0, stream>>>(erow, counts, rank, E);
        scan_block_kernel<<<nb_scan, SCAN_BLK, 0, stream>>>(counts, incl, bsums, N);
        scan_sums_kernel<<<1, SCAN_BLK, 0, stream>>>(bsums, nb_scan);
        finalize_offsets_kernel<<<nb_scan, SCAN_BLK, 0, stream>>>(
            counts, incl, bsums, offsets, N, E);
        fill_kernel<<<eblocks, 256, 0, stream>>>(erow, ecol, ew, offsets, rank, cw, E);

        const int spmm_blocks = (int)((((long long)(N + 1) / 2) * 64 + 255) / 256);

        // ---- layer 0 ----
        gemm_mfma_kernel<false><<<ggrid, 256, 0, stream>>>(h, fc_w, fc_b, s_bf, N, nbatch);
        spmm_csr2_kernel<1><<<spmm_blocks, 256, 0, stream>>>(
            offsets, cw, s_bf, gcn_bias, prelu_a, nullptr, x1_bf, N);
        // ---- layer 1 ----
        gemm_mfma_kernel<true><<<ggrid, 256, 0, stream>>>(
            x1_bf, fc_w + H * H, fc_b + H, s_bf, N, nbatch);
        spmm_csr2_kernel<0><<<spmm_blocks, 256, 0, stream>>>(
            offsets, cw, s_bf, gcn_bias + H, prelu_a + 1, out, nullptr, N);
    } else {
        // ---- fallback: atomic scatter path (needs only s_bf = N*H*2 bytes) ----
        const int total4 = N * (H / 4);
        const int spmm_blocks = (int)(((long long)E * 64 + 255) / 256);

        gemm_mfma_kernel<false><<<ggrid, 256, 0, stream>>>(h, fc_w, fc_b, s_bf, N, nbatch);
        init_out_kernel<<<2048, 256, 0, stream>>>(out, gcn_bias, total4);
        spmm_edge_kernel<<<spmm_blocks, 256, 0, stream>>>(erow, ecol, ew, s_bf, out, E);
        prelu_kernel<<<2048, 256, 0, stream>>>(out, prelu_a, total4);

        gemm_mfma_kernel<false><<<ggrid, 256, 0, stream>>>(out, fc_w + H * H, fc_b + H, s_bf, N, nbatch);
        init_out_kernel<<<2048, 256, 0, stream>>>(out, gcn_bias + H, total4);
        spmm_edge_kernel<<<spmm_blocks, 256, 0, stream>>>(erow, ecol, ew, s_bf, out, E);
        prelu_kernel<<<2048, 256, 0, stream>>>(out, prelu_a + 1, total4);
    }
}

// Round 8
// 157.847 us; speedup vs baseline: 7.4715x; 1.0379x over previous
//
#include <hip/hip_runtime.h>

#define H 128

typedef __attribute__((ext_vector_type(8))) short bf16x8;
typedef __attribute__((ext_vector_type(4))) short s16x4;
typedef __attribute__((ext_vector_type(4))) float f32x4;

__device__ inline unsigned short f2bf(float f) {
    unsigned u = __float_as_uint(f);
    unsigned r = (u + 0x7fffu + ((u >> 16) & 1u)) >> 16;  // RNE
    return (unsigned short)r;
}
__device__ inline float bflo(unsigned u) { return __uint_as_float(u << 16); }
__device__ inline float bfhi(unsigned u) { return __uint_as_float(u & 0xffff0000u); }

// packed edge: col in high 17 bits, weight as 15-bit fixed point (w in [0,1))
__device__ inline unsigned pack_cw(int c, float w) {
    unsigned q = (unsigned)(w * 32768.f);
    if (q > 32767u) q = 32767u;
    return ((unsigned)c << 15) | q;
}

// ===========================================================================
// GEMM body: s_bf[n][j] = bf16( sum_k x[n][k]*W[j][k] + b[j] )
// 256 thr = 4 waves. W staged bf16 in LDS (34 KB, padded rows) once; x frags
// direct global->VGPR; operand-swapped MFMA (D lanes = n, regs = j); 8 B
// packed epilogue stores. 4 blocks/CU (LDS-limited).
// ===========================================================================
#define MB 64

template<bool BF16IN>
__device__ __forceinline__ void gemm_body(
    short* wlds, const void* __restrict__ xv, const float* __restrict__ W,
    const float* __restrict__ b, short* __restrict__ s_out, int N, int nbatch,
    int bid, int grid)
{
    const int t = threadIdx.x;
    const int l = t & 63;
    const int w = t >> 6;
    const int n_g   = (w & 1) * 32;
    const int col_g = (w >> 1) * 64;
    const int ln15 = l & 15;
    const int lhi  = l >> 4;

    #pragma unroll
    for (int i = 0; i < 16; ++i) {
        int fidx = i * 256 + t;          // 4096 float4 chunks
        int j  = fidx >> 5;
        int c4 = fidx & 31;
        float4 v = *reinterpret_cast<const float4*>(W + (size_t)j * H + c4 * 4);
        s16x4 p;
        p[0] = (short)f2bf(v.x); p[1] = (short)f2bf(v.y);
        p[2] = (short)f2bf(v.z); p[3] = (short)f2bf(v.w);
        *reinterpret_cast<s16x4*>(&wlds[j * 136 + c4 * 4]) = p;
    }

    float4 bias4[4];
    #pragma unroll
    for (int jt = 0; jt < 4; ++jt)
        bias4[jt] = *reinterpret_cast<const float4*>(b + col_g + jt * 16 + lhi * 4);

    __syncthreads();   // wlds ready; read-only hereafter

    for (int batch = bid; batch < nbatch; batch += grid) {
        const int row0 = batch * MB;

        bf16x8 ax[4][2];
        #pragma unroll
        for (int nf = 0; nf < 2; ++nf) {
            const int n = row0 + n_g + nf * 16 + ln15;
            const bool ok = (n < N);
            #pragma unroll
            for (int ks = 0; ks < 4; ++ks) {
                bf16x8 f = {0, 0, 0, 0, 0, 0, 0, 0};
                if (ok) {
                    if (BF16IN) {
                        f = *reinterpret_cast<const bf16x8*>(
                            (const short*)xv + (size_t)n * H + ks * 32 + lhi * 8);
                    } else {
                        const float* p = (const float*)xv + (size_t)n * H + ks * 32 + lhi * 8;
                        float4 lo = *reinterpret_cast<const float4*>(p);
                        float4 hi = *reinterpret_cast<const float4*>(p + 4);
                        f[0] = (short)f2bf(lo.x); f[1] = (short)f2bf(lo.y);
                        f[2] = (short)f2bf(lo.z); f[3] = (short)f2bf(lo.w);
                        f[4] = (short)f2bf(hi.x); f[5] = (short)f2bf(hi.y);
                        f[6] = (short)f2bf(hi.z); f[7] = (short)f2bf(hi.w);
                    }
                }
                ax[ks][nf] = f;
            }
        }

        f32x4 acc[2][4] = {};
        #pragma unroll
        for (int ks = 0; ks < 4; ++ks) {
            #pragma unroll
            for (int jt = 0; jt < 4; ++jt) {
                bf16x8 aw = *reinterpret_cast<const bf16x8*>(
                    &wlds[(col_g + jt * 16 + ln15) * 136 + ks * 32 + lhi * 8]);
                acc[0][jt] = __builtin_amdgcn_mfma_f32_16x16x32_bf16(
                    aw, ax[ks][0], acc[0][jt], 0, 0, 0);
                acc[1][jt] = __builtin_amdgcn_mfma_f32_16x16x32_bf16(
                    aw, ax[ks][1], acc[1][jt], 0, 0, 0);
            }
        }

        #pragma unroll
        for (int nf = 0; nf < 2; ++nf) {
            const int n = row0 + n_g + nf * 16 + ln15;
            if (n < N) {
                #pragma unroll
                for (int jt = 0; jt < 4; ++jt) {
                    s16x4 p;
                    p[0] = (short)f2bf(acc[nf][jt][0] + bias4[jt].x);
                    p[1] = (short)f2bf(acc[nf][jt][1] + bias4[jt].y);
                    p[2] = (short)f2bf(acc[nf][jt][2] + bias4[jt].z);
                    p[3] = (short)f2bf(acc[nf][jt][3] + bias4[jt].w);
                    *reinterpret_cast<s16x4*>(
                        s_out + (size_t)n * H + col_g + jt * 16 + lhi * 4) = p;
                }
            }
        }
    }
}

template<bool BF16IN>
__global__ __launch_bounds__(256) void gemm_mfma_kernel(
    const void* __restrict__ xv, const float* __restrict__ W,
    const float* __restrict__ b, short* __restrict__ s_out, int N, int nbatch)
{
    __shared__ short wlds[H * 136];
    gemm_body<BF16IN>(wlds, xv, W, b, s_out, N, nbatch, blockIdx.x, gridDim.x);
}

// Merged dispatch: blocks [0, count_blocks) run count_rank (atomic histogram
// + rank capture, coalesced rank store); the rest run gemm0. Independent work
// overlapped in one dispatch (single stream serializes separate launches).
__global__ __launch_bounds__(256) void count_plus_gemm_kernel(
    const int* __restrict__ erow, int* __restrict__ counts,
    int* __restrict__ rank, int E, int count_blocks,
    const void* __restrict__ xv, const float* __restrict__ W,
    const float* __restrict__ b, short* __restrict__ s_out, int N, int nbatch,
    int gemm_grid)
{
    __shared__ short wlds[H * 136];
    if ((int)blockIdx.x < count_blocks) {
        int e = blockIdx.x * 256 + threadIdx.x;
        if (e < E) rank[e] = atomicAdd(&counts[erow[e]], 1);
        return;
    }
    gemm_body<false>(wlds, xv, W, b, s_out, N, nbatch,
                     (int)blockIdx.x - count_blocks, gemm_grid);
}

// ===========================================================================
// CSR build helpers
// ===========================================================================
__global__ __launch_bounds__(256) void zero_kernel(int4* __restrict__ p, int n4)
{
    int i = blockIdx.x * blockDim.x + threadIdx.x;
    if (i < n4) p[i] = make_int4(0, 0, 0, 0);
}

#define SCAN_BLK 1024
__global__ __launch_bounds__(SCAN_BLK) void scan_block_kernel(
    const int* __restrict__ counts, int* __restrict__ incl,
    int* __restrict__ bsums, int N)
{
    __shared__ int sm[SCAN_BLK];
    int i = blockIdx.x * SCAN_BLK + threadIdx.x;
    int v = (i < N) ? counts[i] : 0;
    sm[threadIdx.x] = v;
    __syncthreads();
    for (int off = 1; off < SCAN_BLK; off <<= 1) {
        int tv = (threadIdx.x >= off) ? sm[threadIdx.x - off] : 0;
        __syncthreads();
        sm[threadIdx.x] += tv;
        __syncthreads();
    }
    if (i < N) incl[i] = sm[threadIdx.x];
    if (threadIdx.x == SCAN_BLK - 1) bsums[blockIdx.x] = sm[SCAN_BLK - 1];
}

// finalize: block b computes its bsums prefix in-kernel (nb <= 1024 values),
// no separate scan_sums launch.
__global__ __launch_bounds__(SCAN_BLK) void finalize_offsets_kernel(
    const int* __restrict__ counts, const int* __restrict__ incl,
    const int* __restrict__ bsums, int* __restrict__ offsets, int N, int E, int nb)
{
    __shared__ int sb[SCAN_BLK];
    int tid = threadIdx.x;
    sb[tid] = (tid < nb) ? bsums[tid] : 0;
    __syncthreads();
    int prefix = 0;
    const int bid = blockIdx.x;
    for (int j = 0; j < bid; ++j) prefix += sb[j];   // LDS broadcast reads

    int i = bid * SCAN_BLK + tid;
    if (i < N) offsets[i] = incl[i] - counts[i] + prefix;
    if (i == 0) offsets[N] = E;
}

// atomic-free fill: pos = offsets[row] + rank (rank captured during count)
__global__ __launch_bounds__(256) void fill_kernel(
    const int* __restrict__ erow, const int* __restrict__ ecol,
    const float* __restrict__ ew, const int* __restrict__ offsets,
    const int* __restrict__ rank, unsigned* __restrict__ cw, int E)
{
    int e = blockIdx.x * blockDim.x + threadIdx.x;
    if (e < E) {
        int r = erow[e];
        cw[offsets[r] + rank[e]] = pack_cw(ecol[e], ew[e]);
    }
}

// ===========================================================================
// SpMM v2 (CSR, gather-only, bf16 s, packed 4B edges) + gcn_bias + PReLU.
// One wave = 2 rows; half-wave (32 lanes) per row, lane li owns cols
// [4li, 4li+3] (u64 load = 4 bf16). 4-deep unrolled accumulator chains.
// MODE: 0 = write f32 out (float4), 1 = write bf16 out (8 B pack).
// ===========================================================================
template<int MODE>
__global__ __launch_bounds__(256) void spmm_csr2_kernel(
    const int* __restrict__ offsets, const unsigned* __restrict__ cw,
    const short* __restrict__ s_bf, const float* __restrict__ gbias,
    const float* __restrict__ a_ptr, float* __restrict__ out_f,
    short* __restrict__ out_b, int N)
{
    const float a = a_ptr[0];
    int gid = blockIdx.x * blockDim.x + threadIdx.x;
    int wid  = gid >> 6;
    int l    = gid & 63;
    int half = l >> 5;
    int li   = l & 31;
    int r = wid * 2 + half;
    if (r >= N) return;

    const int beg = offsets[r], end = offsets[r + 1];
    const size_t coff = (size_t)li * 4;
    const float SC = 1.f / 32768.f;

    float a00=0.f,a01=0.f,a02=0.f,a03=0.f;
    float a10=0.f,a11=0.f,a12=0.f,a13=0.f;
    float a20=0.f,a21=0.f,a22=0.f,a23=0.f;
    float a30=0.f,a31=0.f,a32=0.f,a33=0.f;

    int e = beg;
    for (; e + 4 <= end; e += 4) {
        unsigned p0 = cw[e],     p1 = cw[e + 1];
        unsigned p2 = cw[e + 2], p3 = cw[e + 3];
        float w0 = (float)(p0 & 0x7fffu) * SC;
        float w1 = (float)(p1 & 0x7fffu) * SC;
        float w2 = (float)(p2 & 0x7fffu) * SC;
        float w3 = (float)(p3 & 0x7fffu) * SC;
        unsigned long long u0 = *reinterpret_cast<const unsigned long long*>(
            s_bf + (size_t)(p0 >> 15) * H + coff);
        unsigned long long u1 = *reinterpret_cast<const unsigned long long*>(
            s_bf + (size_t)(p1 >> 15) * H + coff);
        unsigned long long u2 = *reinterpret_cast<const unsigned long long*>(
            s_bf + (size_t)(p2 >> 15) * H + coff);
        unsigned long long u3 = *reinterpret_cast<const unsigned long long*>(
            s_bf + (size_t)(p3 >> 15) * H + coff);
        unsigned lo;
        lo = (unsigned)u0; a00 += w0 * bflo(lo); a01 += w0 * bfhi(lo);
        lo = (unsigned)(u0 >> 32); a02 += w0 * bflo(lo); a03 += w0 * bfhi(lo);
        lo = (unsigned)u1; a10 += w1 * bflo(lo); a11 += w1 * bfhi(lo);
        lo = (unsigned)(u1 >> 32); a12 += w1 * bflo(lo); a13 += w1 * bfhi(lo);
        lo = (unsigned)u2; a20 += w2 * bflo(lo); a21 += w2 * bfhi(lo);
        lo = (unsigned)(u2 >> 32); a22 += w2 * bflo(lo); a23 += w2 * bfhi(lo);
        lo = (unsigned)u3; a30 += w3 * bflo(lo); a31 += w3 * bfhi(lo);
        lo = (unsigned)(u3 >> 32); a32 += w3 * bflo(lo); a33 += w3 * bfhi(lo);
    }
    for (; e < end; ++e) {
        unsigned p0 = cw[e];
        float w0 = (float)(p0 & 0x7fffu) * SC;
        unsigned long long u0 = *reinterpret_cast<const unsigned long long*>(
            s_bf + (size_t)(p0 >> 15) * H + coff);
        unsigned lo;
        lo = (unsigned)u0; a00 += w0 * bflo(lo); a01 += w0 * bfhi(lo);
        lo = (unsigned)(u0 >> 32); a02 += w0 * bflo(lo); a03 += w0 * bfhi(lo);
    }

    float4 g = *reinterpret_cast<const float4*>(gbias + li * 4);
    float v0 = (a00 + a10) + (a20 + a30) + g.x;
    float v1 = (a01 + a11) + (a21 + a31) + g.y;
    float v2 = (a02 + a12) + (a22 + a32) + g.z;
    float v3 = (a03 + a13) + (a23 + a33) + g.w;
    v0 = v0 > 0.f ? v0 : a * v0;
    v1 = v1 > 0.f ? v1 : a * v1;
    v2 = v2 > 0.f ? v2 : a * v2;
    v3 = v3 > 0.f ? v3 : a * v3;

    if (MODE == 0) {
        *reinterpret_cast<float4*>(out_f + (size_t)r * H + li * 4) =
            make_float4(v0, v1, v2, v3);
    } else {
        s16x4 p;
        p[0] = (short)f2bf(v0); p[1] = (short)f2bf(v1);
        p[2] = (short)f2bf(v2); p[3] = (short)f2bf(v3);
        *reinterpret_cast<s16x4*>(out_b + (size_t)r * H + li * 4) = p;
    }
}

// ===========================================================================
// Fallback path (ws too small for CSR): atomic scatter SpMM over bf16 s
// ===========================================================================
__global__ __launch_bounds__(256) void init_out_kernel(
    float* __restrict__ out, const float* __restrict__ gbias, int total4)
{
    int i = blockIdx.x * blockDim.x + threadIdx.x;
    const int stride = gridDim.x * blockDim.x;
    for (; i < total4; i += stride) {
        int c4 = i & 31;
        float4 bv = *reinterpret_cast<const float4*>(gbias + c4 * 4);
        *reinterpret_cast<float4*>(out + (size_t)i * 4) = bv;
    }
}

__global__ __launch_bounds__(256) void spmm_edge_kernel(
    const int* __restrict__ erow, const int* __restrict__ ecol,
    const float* __restrict__ ew, const short* __restrict__ s_bf,
    float* __restrict__ out, int E)
{
    long long gid = (long long)blockIdx.x * blockDim.x + threadIdx.x;
    int e = (int)(gid >> 6);
    int l = (int)(gid & 63);
    if (e >= E) return;
    int r = erow[e];
    int c = ecol[e];
    float w = ew[e];
    unsigned u = *reinterpret_cast<const unsigned*>(s_bf + (size_t)c * H + 2 * l);
    unsafeAtomicAdd(out + (size_t)r * H + l * 2 + 0, bflo(u) * w);
    unsafeAtomicAdd(out + (size_t)r * H + l * 2 + 1, bfhi(u) * w);
}

__global__ __launch_bounds__(256) void prelu_kernel(
    float* __restrict__ buf, const float* __restrict__ a_ptr, int total4)
{
    const float a = a_ptr[0];
    int i = blockIdx.x * blockDim.x + threadIdx.x;
    const int stride = gridDim.x * blockDim.x;
    for (; i < total4; i += stride) {
        float4 v = *reinterpret_cast<float4*>(buf + (size_t)i * 4);
        v.x = v.x > 0.f ? v.x : a * v.x;
        v.y = v.y > 0.f ? v.y : a * v.y;
        v.z = v.z > 0.f ? v.z : a * v.z;
        v.w = v.w > 0.f ? v.w : a * v.w;
        *reinterpret_cast<float4*>(buf + (size_t)i * 4) = v;
    }
}

// ===========================================================================
extern "C" void kernel_launch(void* const* d_in, const int* in_sizes, int n_in,
                              void* d_out, int out_size, void* d_ws, size_t ws_size,
                              hipStream_t stream)
{
    const float* h        = (const float*)d_in[0];
    const int*   erow     = (const int*)d_in[1];
    const int*   ecol     = (const int*)d_in[2];
    const float* ew       = (const float*)d_in[3];
    const float* fc_w     = (const float*)d_in[4];  // [2][H][H]
    const float* fc_b     = (const float*)d_in[5];  // [2][H]
    const float* gcn_bias = (const float*)d_in[6];  // [2][H]
    const float* prelu_a  = (const float*)d_in[7];  // [2]

    const int N = in_sizes[0] / H;
    const int E = in_sizes[1];
    float* out = (float*)d_out;

    // ---- workspace layout ----
    char* ws = (char*)d_ws;
    short* s_bf  = (short*)ws;                       // N*H bf16 (GEMM out / spmm in)
    size_t off = (size_t)N * H * sizeof(short);
    short* x1_bf = (short*)(ws + off); off += (size_t)N * H * sizeof(short);
    off = (off + 15) & ~(size_t)15;                  // 16B align for int4 zero
    int* counts  = (int*)(ws + off); off += (size_t)((N + 3) & ~3) * 4;
    int* incl    = (int*)(ws + off); off += (size_t)N * 4;
    int* offsets = (int*)(ws + off); off += (size_t)(N + 1) * 4;
    const int nb_scan = (N + SCAN_BLK - 1) / SCAN_BLK;
    int* bsums   = (int*)(ws + off); off += (size_t)nb_scan * 4;
    int* rank    = (int*)(ws + off); off += (size_t)E * 4;
    unsigned* cw = (unsigned*)(ws + off); off += (size_t)E * 4;

    const int eblocks = (E + 255) / 256;
    const int nbatch = (N + MB - 1) / MB;
    const int ggrid = nbatch < 1024 ? nbatch : 1024;

    if (off <= ws_size) {
        const int n4 = (N + 3) / 4;
        // ---- zero counts (custom kernel; rocclr fillBuffer was 40 us) ----
        zero_kernel<<<(n4 + 255) / 256, 256, 0, stream>>>((int4*)counts, n4);
        // ---- count_rank overlapped with gemm0 (independent work) ----
        count_plus_gemm_kernel<<<eblocks + ggrid, 256, 0, stream>>>(
            erow, counts, rank, E, eblocks,
            h, fc_w, fc_b, s_bf, N, nbatch, ggrid);
        // ---- offsets ----
        scan_block_kernel<<<nb_scan, SCAN_BLK, 0, stream>>>(counts, incl, bsums, N);
        finalize_offsets_kernel<<<nb_scan, SCAN_BLK, 0, stream>>>(
            counts, incl, bsums, offsets, N, E, nb_scan);
        // ---- atomic-free fill ----
        fill_kernel<<<eblocks, 256, 0, stream>>>(erow, ecol, ew, offsets, rank, cw, E);

        const int spmm_blocks = (int)((((long long)(N + 1) / 2) * 64 + 255) / 256);

        // ---- layer 0 tail ----
        spmm_csr2_kernel<1><<<spmm_blocks, 256, 0, stream>>>(
            offsets, cw, s_bf, gcn_bias, prelu_a, nullptr, x1_bf, N);
        // ---- layer 1 ----
        gemm_mfma_kernel<true><<<ggrid, 256, 0, stream>>>(
            x1_bf, fc_w + H * H, fc_b + H, s_bf, N, nbatch);
        spmm_csr2_kernel<0><<<spmm_blocks, 256, 0, stream>>>(
            offsets, cw, s_bf, gcn_bias + H, prelu_a + 1, out, nullptr, N);
    } else {
        // ---- fallback: atomic scatter path (needs only s_bf = N*H*2 bytes) ----
        const int total4 = N * (H / 4);
        const int spmm_blocks = (int)(((long long)E * 64 + 255) / 256);

        gemm_mfma_kernel<false><<<ggrid, 256, 0, stream>>>(h, fc_w, fc_b, s_bf, N, nbatch);
        init_out_kernel<<<2048, 256, 0, stream>>>(out, gcn_bias, total4);
        spmm_edge_kernel<<<spmm_blocks, 256, 0, stream>>>(erow, ecol, ew, s_bf, out, E);
        prelu_kernel<<<2048, 256, 0, stream>>>(out, prelu_a, total4);

        gemm_mfma_kernel<false><<<ggrid, 256, 0, stream>>>(out, fc_w + H * H, fc_b + H, s_bf, N, nbatch);
        init_out_kernel<<<2048, 256, 0, stream>>>(out, gcn_bias + H, total4);
        spmm_edge_kernel<<<spmm_blocks, 256, 0, stream>>>(erow, ecol, ew, s_bf, out, E);
        prelu_kernel<<<2048, 256, 0, stream>>>(out, prelu_a + 1, total4);
    }
}

// Round 9
// 156.239 us; speedup vs baseline: 7.5484x; 1.0103x over previous
//
#include <hip/hip_runtime.h>

#define H 128

typedef __attribute__((ext_vector_type(8))) short bf16x8;
typedef __attribute__((ext_vector_type(4))) short s16x4;
typedef __attribute__((ext_vector_type(4))) float f32x4;

__device__ inline unsigned short f2bf(float f) {
    unsigned u = __float_as_uint(f);
    unsigned r = (u + 0x7fffu + ((u >> 16) & 1u)) >> 16;  // RNE
    return (unsigned short)r;
}
__device__ inline float bflo(unsigned u) { return __uint_as_float(u << 16); }
__device__ inline float bfhi(unsigned u) { return __uint_as_float(u & 0xffff0000u); }

// packed edge: col in high 17 bits, weight as 15-bit fixed point (w in [0,1))
__device__ inline unsigned pack_cw(int c, float w) {
    unsigned q = (unsigned)(w * 32768.f);
    if (q > 32767u) q = 32767u;
    return ((unsigned)c << 15) | q;
}

// ===========================================================================
// GEMM: s_bf[n][j] = bf16( sum_k x[n][k]*W[j][k] + b[j] )
// 256 thr = 4 waves. W staged bf16 in LDS (34 KB, padded rows) once; x frags
// direct global->VGPR; operand-swapped MFMA (D lanes = n, regs = j); 8 B
// packed epilogue stores. 4 blocks/CU (LDS-limited).
// ===========================================================================
#define MB 64

template<bool BF16IN>
__global__ __launch_bounds__(256) void gemm_mfma_kernel(
    const void* __restrict__ xv, const float* __restrict__ W,
    const float* __restrict__ b, short* __restrict__ s_out, int N, int nbatch)
{
    __shared__ short wlds[H * 136];

    const int t = threadIdx.x;
    const int l = t & 63;
    const int w = t >> 6;
    const int n_g   = (w & 1) * 32;
    const int col_g = (w >> 1) * 64;
    const int ln15 = l & 15;
    const int lhi  = l >> 4;

    #pragma unroll
    for (int i = 0; i < 16; ++i) {
        int fidx = i * 256 + t;          // 4096 float4 chunks
        int j  = fidx >> 5;
        int c4 = fidx & 31;
        float4 v = *reinterpret_cast<const float4*>(W + (size_t)j * H + c4 * 4);
        s16x4 p;
        p[0] = (short)f2bf(v.x); p[1] = (short)f2bf(v.y);
        p[2] = (short)f2bf(v.z); p[3] = (short)f2bf(v.w);
        *reinterpret_cast<s16x4*>(&wlds[j * 136 + c4 * 4]) = p;
    }

    float4 bias4[4];
    #pragma unroll
    for (int jt = 0; jt < 4; ++jt)
        bias4[jt] = *reinterpret_cast<const float4*>(b + col_g + jt * 16 + lhi * 4);

    __syncthreads();   // wlds ready; read-only hereafter

    for (int batch = blockIdx.x; batch < nbatch; batch += gridDim.x) {
        const int row0 = batch * MB;

        bf16x8 ax[4][2];
        #pragma unroll
        for (int nf = 0; nf < 2; ++nf) {
            const int n = row0 + n_g + nf * 16 + ln15;
            const bool ok = (n < N);
            #pragma unroll
            for (int ks = 0; ks < 4; ++ks) {
                bf16x8 f = {0, 0, 0, 0, 0, 0, 0, 0};
                if (ok) {
                    if (BF16IN) {
                        f = *reinterpret_cast<const bf16x8*>(
                            (const short*)xv + (size_t)n * H + ks * 32 + lhi * 8);
                    } else {
                        const float* p = (const float*)xv + (size_t)n * H + ks * 32 + lhi * 8;
                        float4 lo = *reinterpret_cast<const float4*>(p);
                        float4 hi = *reinterpret_cast<const float4*>(p + 4);
                        f[0] = (short)f2bf(lo.x); f[1] = (short)f2bf(lo.y);
                        f[2] = (short)f2bf(lo.z); f[3] = (short)f2bf(lo.w);
                        f[4] = (short)f2bf(hi.x); f[5] = (short)f2bf(hi.y);
                        f[6] = (short)f2bf(hi.z); f[7] = (short)f2bf(hi.w);
                    }
                }
                ax[ks][nf] = f;
            }
        }

        f32x4 acc[2][4] = {};
        #pragma unroll
        for (int ks = 0; ks < 4; ++ks) {
            #pragma unroll
            for (int jt = 0; jt < 4; ++jt) {
                bf16x8 aw = *reinterpret_cast<const bf16x8*>(
                    &wlds[(col_g + jt * 16 + ln15) * 136 + ks * 32 + lhi * 8]);
                acc[0][jt] = __builtin_amdgcn_mfma_f32_16x16x32_bf16(
                    aw, ax[ks][0], acc[0][jt], 0, 0, 0);
                acc[1][jt] = __builtin_amdgcn_mfma_f32_16x16x32_bf16(
                    aw, ax[ks][1], acc[1][jt], 0, 0, 0);
            }
        }

        #pragma unroll
        for (int nf = 0; nf < 2; ++nf) {
            const int n = row0 + n_g + nf * 16 + ln15;
            if (n < N) {
                #pragma unroll
                for (int jt = 0; jt < 4; ++jt) {
                    s16x4 p;
                    p[0] = (short)f2bf(acc[nf][jt][0] + bias4[jt].x);
                    p[1] = (short)f2bf(acc[nf][jt][1] + bias4[jt].y);
                    p[2] = (short)f2bf(acc[nf][jt][2] + bias4[jt].z);
                    p[3] = (short)f2bf(acc[nf][jt][3] + bias4[jt].w);
                    *reinterpret_cast<s16x4*>(
                        s_out + (size_t)n * H + col_g + jt * 16 + lhi * 4) = p;
                }
            }
        }
    }
}

// ===========================================================================
// CSR build helpers (no LDS in count/fill -> full occupancy, short-lived)
// ===========================================================================
__global__ __launch_bounds__(256) void zero_kernel(int4* __restrict__ p, int n4)
{
    int i = blockIdx.x * blockDim.x + threadIdx.x;
    if (i < n4) p[i] = make_int4(0, 0, 0, 0);
}

__global__ __launch_bounds__(256) void count_rank_kernel(
    const int* __restrict__ erow, int* __restrict__ counts,
    int* __restrict__ rank, int E)
{
    int e = blockIdx.x * blockDim.x + threadIdx.x;
    if (e < E) rank[e] = atomicAdd(&counts[erow[e]], 1);
}

#define SCAN_BLK 1024
__global__ __launch_bounds__(SCAN_BLK) void scan_block_kernel(
    const int* __restrict__ counts, int* __restrict__ incl,
    int* __restrict__ bsums, int N)
{
    __shared__ int sm[SCAN_BLK];
    int i = blockIdx.x * SCAN_BLK + threadIdx.x;
    int v = (i < N) ? counts[i] : 0;
    sm[threadIdx.x] = v;
    __syncthreads();
    for (int off = 1; off < SCAN_BLK; off <<= 1) {
        int tv = (threadIdx.x >= off) ? sm[threadIdx.x - off] : 0;
        __syncthreads();
        sm[threadIdx.x] += tv;
        __syncthreads();
    }
    if (i < N) incl[i] = sm[threadIdx.x];
    if (threadIdx.x == SCAN_BLK - 1) bsums[blockIdx.x] = sm[SCAN_BLK - 1];
}

// finalize: block b computes its bsums prefix in-kernel (nb <= 1024 values)
__global__ __launch_bounds__(SCAN_BLK) void finalize_offsets_kernel(
    const int* __restrict__ counts, const int* __restrict__ incl,
    const int* __restrict__ bsums, int* __restrict__ offsets, int N, int E, int nb)
{
    __shared__ int sb[SCAN_BLK];
    int tid = threadIdx.x;
    sb[tid] = (tid < nb) ? bsums[tid] : 0;
    __syncthreads();
    int prefix = 0;
    const int bid = blockIdx.x;
    for (int j = 0; j < bid; ++j) prefix += sb[j];   // LDS broadcast reads

    int i = bid * SCAN_BLK + tid;
    if (i < N) offsets[i] = incl[i] - counts[i] + prefix;
    if (i == 0) offsets[N] = E;
}

// atomic-free fill: pos = offsets[row] + rank (rank captured during count)
__global__ __launch_bounds__(256) void fill_kernel(
    const int* __restrict__ erow, const int* __restrict__ ecol,
    const float* __restrict__ ew, const int* __restrict__ offsets,
    const int* __restrict__ rank, unsigned* __restrict__ cw, int E)
{
    int e = blockIdx.x * blockDim.x + threadIdx.x;
    if (e < E) {
        int r = erow[e];
        cw[offsets[r] + rank[e]] = pack_cw(ecol[e], ew[e]);
    }
}

// ===========================================================================
// SpMM v3 (CSR, gather-only, bf16 s, packed 4B edges) + gcn_bias + PReLU.
// Quarter-wave per row: 16 lanes/row, 4 rows/wave; lane li owns cols
// [8li, 8li+7] (uint4 load = 8 bf16 = 16 B). 4-edge unroll.
// MODE: 0 = write f32 out (2x float4), 1 = write bf16 out (16 B).
// ===========================================================================
template<int MODE>
__global__ __launch_bounds__(256) void spmm_csr3_kernel(
    const int* __restrict__ offsets, const unsigned* __restrict__ cw,
    const short* __restrict__ s_bf, const float* __restrict__ gbias,
    const float* __restrict__ a_ptr, float* __restrict__ out_f,
    short* __restrict__ out_b, int N)
{
    const float a = a_ptr[0];
    int gid = blockIdx.x * blockDim.x + threadIdx.x;
    int wid = gid >> 6;
    int l   = gid & 63;
    int sub = l >> 4;      // row within wave (0..3)
    int li  = l & 15;      // lane within row
    int r = wid * 4 + sub;
    if (r >= N) return;

    const int beg = offsets[r], end = offsets[r + 1];
    const size_t coff = (size_t)li * 8;
    const float SC = 1.f / 32768.f;

    float a0=0.f,a1=0.f,a2=0.f,a3=0.f,a4=0.f,a5=0.f,a6=0.f,a7=0.f;

    int e = beg;
    for (; e + 4 <= end; e += 4) {
        unsigned p0 = cw[e],     p1 = cw[e + 1];
        unsigned p2 = cw[e + 2], p3 = cw[e + 3];
        float w0 = (float)(p0 & 0x7fffu) * SC;
        float w1 = (float)(p1 & 0x7fffu) * SC;
        float w2 = (float)(p2 & 0x7fffu) * SC;
        float w3 = (float)(p3 & 0x7fffu) * SC;
        uint4 u0 = *reinterpret_cast<const uint4*>(s_bf + (size_t)(p0 >> 15) * H + coff);
        uint4 u1 = *reinterpret_cast<const uint4*>(s_bf + (size_t)(p1 >> 15) * H + coff);
        uint4 u2 = *reinterpret_cast<const uint4*>(s_bf + (size_t)(p2 >> 15) * H + coff);
        uint4 u3 = *reinterpret_cast<const uint4*>(s_bf + (size_t)(p3 >> 15) * H + coff);
        a0 += w0 * bflo(u0.x); a1 += w0 * bfhi(u0.x);
        a2 += w0 * bflo(u0.y); a3 += w0 * bfhi(u0.y);
        a4 += w0 * bflo(u0.z); a5 += w0 * bfhi(u0.z);
        a6 += w0 * bflo(u0.w); a7 += w0 * bfhi(u0.w);
        a0 += w1 * bflo(u1.x); a1 += w1 * bfhi(u1.x);
        a2 += w1 * bflo(u1.y); a3 += w1 * bfhi(u1.y);
        a4 += w1 * bflo(u1.z); a5 += w1 * bfhi(u1.z);
        a6 += w1 * bflo(u1.w); a7 += w1 * bfhi(u1.w);
        a0 += w2 * bflo(u2.x); a1 += w2 * bfhi(u2.x);
        a2 += w2 * bflo(u2.y); a3 += w2 * bfhi(u2.y);
        a4 += w2 * bflo(u2.z); a5 += w2 * bfhi(u2.z);
        a6 += w2 * bflo(u2.w); a7 += w2 * bfhi(u2.w);
        a0 += w3 * bflo(u3.x); a1 += w3 * bfhi(u3.x);
        a2 += w3 * bflo(u3.y); a3 += w3 * bfhi(u3.y);
        a4 += w3 * bflo(u3.z); a5 += w3 * bfhi(u3.z);
        a6 += w3 * bflo(u3.w); a7 += w3 * bfhi(u3.w);
    }
    for (; e < end; ++e) {
        unsigned p0 = cw[e];
        float w0 = (float)(p0 & 0x7fffu) * SC;
        uint4 u0 = *reinterpret_cast<const uint4*>(s_bf + (size_t)(p0 >> 15) * H + coff);
        a0 += w0 * bflo(u0.x); a1 += w0 * bfhi(u0.x);
        a2 += w0 * bflo(u0.y); a3 += w0 * bfhi(u0.y);
        a4 += w0 * bflo(u0.z); a5 += w0 * bfhi(u0.z);
        a6 += w0 * bflo(u0.w); a7 += w0 * bfhi(u0.w);
    }

    float4 g0 = *reinterpret_cast<const float4*>(gbias + li * 8);
    float4 g1 = *reinterpret_cast<const float4*>(gbias + li * 8 + 4);
    float v0 = a0 + g0.x, v1 = a1 + g0.y, v2 = a2 + g0.z, v3 = a3 + g0.w;
    float v4 = a4 + g1.x, v5 = a5 + g1.y, v6 = a6 + g1.z, v7 = a7 + g1.w;
    v0 = v0 > 0.f ? v0 : a * v0;  v1 = v1 > 0.f ? v1 : a * v1;
    v2 = v2 > 0.f ? v2 : a * v2;  v3 = v3 > 0.f ? v3 : a * v3;
    v4 = v4 > 0.f ? v4 : a * v4;  v5 = v5 > 0.f ? v5 : a * v5;
    v6 = v6 > 0.f ? v6 : a * v6;  v7 = v7 > 0.f ? v7 : a * v7;

    if (MODE == 0) {
        *reinterpret_cast<float4*>(out_f + (size_t)r * H + li * 8) =
            make_float4(v0, v1, v2, v3);
        *reinterpret_cast<float4*>(out_f + (size_t)r * H + li * 8 + 4) =
            make_float4(v4, v5, v6, v7);
    } else {
        bf16x8 p;
        p[0] = (short)f2bf(v0); p[1] = (short)f2bf(v1);
        p[2] = (short)f2bf(v2); p[3] = (short)f2bf(v3);
        p[4] = (short)f2bf(v4); p[5] = (short)f2bf(v5);
        p[6] = (short)f2bf(v6); p[7] = (short)f2bf(v7);
        *reinterpret_cast<bf16x8*>(out_b + (size_t)r * H + li * 8) = p;
    }
}

// ===========================================================================
// Fallback path (ws too small for CSR): atomic scatter SpMM over bf16 s
// ===========================================================================
__global__ __launch_bounds__(256) void init_out_kernel(
    float* __restrict__ out, const float* __restrict__ gbias, int total4)
{
    int i = blockIdx.x * blockDim.x + threadIdx.x;
    const int stride = gridDim.x * blockDim.x;
    for (; i < total4; i += stride) {
        int c4 = i & 31;
        float4 bv = *reinterpret_cast<const float4*>(gbias + c4 * 4);
        *reinterpret_cast<float4*>(out + (size_t)i * 4) = bv;
    }
}

__global__ __launch_bounds__(256) void spmm_edge_kernel(
    const int* __restrict__ erow, const int* __restrict__ ecol,
    const float* __restrict__ ew, const short* __restrict__ s_bf,
    float* __restrict__ out, int E)
{
    long long gid = (long long)blockIdx.x * blockDim.x + threadIdx.x;
    int e = (int)(gid >> 6);
    int l = (int)(gid & 63);
    if (e >= E) return;
    int r = erow[e];
    int c = ecol[e];
    float w = ew[e];
    unsigned u = *reinterpret_cast<const unsigned*>(s_bf + (size_t)c * H + 2 * l);
    unsafeAtomicAdd(out + (size_t)r * H + l * 2 + 0, bflo(u) * w);
    unsafeAtomicAdd(out + (size_t)r * H + l * 2 + 1, bfhi(u) * w);
}

__global__ __launch_bounds__(256) void prelu_kernel(
    float* __restrict__ buf, const float* __restrict__ a_ptr, int total4)
{
    const float a = a_ptr[0];
    int i = blockIdx.x * blockDim.x + threadIdx.x;
    const int stride = gridDim.x * blockDim.x;
    for (; i < total4; i += stride) {
        float4 v = *reinterpret_cast<float4*>(buf + (size_t)i * 4);
        v.x = v.x > 0.f ? v.x : a * v.x;
        v.y = v.y > 0.f ? v.y : a * v.y;
        v.z = v.z > 0.f ? v.z : a * v.z;
        v.w = v.w > 0.f ? v.w : a * v.w;
        *reinterpret_cast<float4*>(buf + (size_t)i * 4) = v;
    }
}

// ===========================================================================
extern "C" void kernel_launch(void* const* d_in, const int* in_sizes, int n_in,
                              void* d_out, int out_size, void* d_ws, size_t ws_size,
                              hipStream_t stream)
{
    const float* h        = (const float*)d_in[0];
    const int*   erow     = (const int*)d_in[1];
    const int*   ecol     = (const int*)d_in[2];
    const float* ew       = (const float*)d_in[3];
    const float* fc_w     = (const float*)d_in[4];  // [2][H][H]
    const float* fc_b     = (const float*)d_in[5];  // [2][H]
    const float* gcn_bias = (const float*)d_in[6];  // [2][H]
    const float* prelu_a  = (const float*)d_in[7];  // [2]

    const int N = in_sizes[0] / H;
    const int E = in_sizes[1];
    float* out = (float*)d_out;

    // ---- workspace layout ----
    char* ws = (char*)d_ws;
    short* s_bf  = (short*)ws;                       // N*H bf16 (GEMM out / spmm in)
    size_t off = (size_t)N * H * sizeof(short);
    short* x1_bf = (short*)(ws + off); off += (size_t)N * H * sizeof(short);
    off = (off + 15) & ~(size_t)15;                  // 16B align for int4 zero
    int* counts  = (int*)(ws + off); off += (size_t)((N + 3) & ~3) * 4;
    int* incl    = (int*)(ws + off); off += (size_t)N * 4;
    int* offsets = (int*)(ws + off); off += (size_t)(N + 1) * 4;
    const int nb_scan = (N + SCAN_BLK - 1) / SCAN_BLK;
    int* bsums   = (int*)(ws + off); off += (size_t)nb_scan * 4;
    int* rank    = (int*)(ws + off); off += (size_t)E * 4;
    unsigned* cw = (unsigned*)(ws + off); off += (size_t)E * 4;

    const int eblocks = (E + 255) / 256;
    const int nbatch = (N + MB - 1) / MB;
    const int ggrid = nbatch < 1024 ? nbatch : 1024;

    if (off <= ws_size) {
        const int n4 = (N + 3) / 4;
        // ---- CSR build (all small, full-occupancy kernels) ----
        zero_kernel<<<(n4 + 255) / 256, 256, 0, stream>>>((int4*)counts, n4);
        count_rank_kernel<<<eblocks, 256, 0, stream>>>(erow, counts, rank, E);
        scan_block_kernel<<<nb_scan, SCAN_BLK, 0, stream>>>(counts, incl, bsums, N);
        finalize_offsets_kernel<<<nb_scan, SCAN_BLK, 0, stream>>>(
            counts, incl, bsums, offsets, N, E, nb_scan);
        fill_kernel<<<eblocks, 256, 0, stream>>>(erow, ecol, ew, offsets, rank, cw, E);

        const int spmm_blocks = (int)(((long long)N * 16 + 255) / 256);

        // ---- layer 0 ----
        gemm_mfma_kernel<false><<<ggrid, 256, 0, stream>>>(h, fc_w, fc_b, s_bf, N, nbatch);
        spmm_csr3_kernel<1><<<spmm_blocks, 256, 0, stream>>>(
            offsets, cw, s_bf, gcn_bias, prelu_a, nullptr, x1_bf, N);
        // ---- layer 1 ----
        gemm_mfma_kernel<true><<<ggrid, 256, 0, stream>>>(
            x1_bf, fc_w + H * H, fc_b + H, s_bf, N, nbatch);
        spmm_csr3_kernel<0><<<spmm_blocks, 256, 0, stream>>>(
            offsets, cw, s_bf, gcn_bias + H, prelu_a + 1, out, nullptr, N);
    } else {
        // ---- fallback: atomic scatter path (needs only s_bf = N*H*2 bytes) ----
        const int total4 = N * (H / 4);
        const int spmm_blocks = (int)(((long long)E * 64 + 255) / 256);

        gemm_mfma_kernel<false><<<ggrid, 256, 0, stream>>>(h, fc_w, fc_b, s_bf, N, nbatch);
        init_out_kernel<<<2048, 256, 0, stream>>>(out, gcn_bias, total4);
        spmm_edge_kernel<<<spmm_blocks, 256, 0, stream>>>(erow, ecol, ew, s_bf, out, E);
        prelu_kernel<<<2048, 256, 0, stream>>>(out, prelu_a, total4);

        gemm_mfma_kernel<false><<<ggrid, 256, 0, stream>>>(out, fc_w + H * H, fc_b + H, s_bf, N, nbatch);
        init_out_kernel<<<2048, 256, 0, stream>>>(out, gcn_bias + H, total4);
        spmm_edge_kernel<<<spmm_blocks, 256, 0, stream>>>(erow, ecol, ew, s_bf, out, E);
        prelu_kernel<<<2048, 256, 0, stream>>>(out, prelu_a + 1, total4);
    }
}